// Round 5
// baseline (1142.873 us; speedup 1.0000x reference)
//
#include <hip/hip_runtime.h>
#include <math.h>

typedef float f32x4 __attribute__((ext_vector_type(4)));
typedef unsigned short u16x8 __attribute__((ext_vector_type(8)));
typedef unsigned short u16x4 __attribute__((ext_vector_type(4)));
typedef __bf16 bf16x8 __attribute__((ext_vector_type(8)));
typedef unsigned int u32;

#define DEV static __device__ __forceinline__

DEV unsigned short f2bf(float f) {            // RNE f32 -> bf16 bits
  unsigned u = __float_as_uint(f);
  u += 0x7FFFu + ((u >> 16) & 1u);
  return (unsigned short)(u >> 16);
}
DEV float bf2f(unsigned short s) { return __uint_as_float(((unsigned)s) << 16); }
DEV bf16x8 asbf(u16x8 v) { return __builtin_bit_cast(bf16x8, v); }

DEV void gload16(const void* g, void* l) {    // async global->LDS, 16B/lane, wave-uniform LDS base
  __builtin_amdgcn_global_load_lds((const __attribute__((address_space(1))) u32*)g,
                                   (__attribute__((address_space(3))) u32*)l, 16, 0, 0);
}

// ---------------------------------------------------------------- f32 -> bf16 bulk convert
__global__ void cvt_kernel(const float* __restrict__ in, unsigned short* __restrict__ out, int n8) {
  for (int i = blockIdx.x * 256 + threadIdx.x; i < n8; i += gridDim.x * 256) {
    const float* s = in + (size_t)i * 8;
    f32x4 a = *(const f32x4*)s, b = *(const f32x4*)(s + 4);
    u16x8 o;
    for (int j = 0; j < 4; ++j) { o[j] = f2bf(a[j]); o[j + 4] = f2bf(b[j]); }
    *(u16x8*)(out + (size_t)i * 8) = o;
  }
}

// ---------------------------------------------------------------- embed
__global__ void embed_kernel(const int* __restrict__ x, const float* __restrict__ tok,
                             const float* __restrict__ pos, float* __restrict__ h,
                             unsigned short* __restrict__ hbf) {
  int t = blockIdx.x, tid = threadIdx.x;
  int v = x[t], s = t & 1023;                 // S = 1024
  f32x4 a = *(const f32x4*)(tok + (size_t)v * 1024 + tid * 4);
  f32x4 b = *(const f32x4*)(pos + (size_t)s * 1024 + tid * 4);
  f32x4 r = a + b;
  *(f32x4*)(h + (size_t)t * 1024 + tid * 4) = r;
  u16x4 rb;
  for (int i = 0; i < 4; ++i) rb[i] = f2bf(r[i]);
  *(u16x4*)(hbf + (size_t)t * 1024 + tid * 4) = rb;
}

// ---------------------------------------------------------------- LayerNorm(preA + preB + res)
__global__ __launch_bounds__(256) void ln_kernel(const float* __restrict__ preA,
    const float* __restrict__ preB, const float* __restrict__ res,
    const float* __restrict__ g, const float* __restrict__ bta,
    float* __restrict__ outf, unsigned short* __restrict__ outbf) {
  int row = blockIdx.x, tid = threadIdx.x;
  size_t base = (size_t)row * 1024 + tid * 4;
  f32x4 xv = *(const f32x4*)(preA + base);
  xv += *(const f32x4*)(preB + base);
  xv += *(const f32x4*)(res + base);
  float s = xv[0] + xv[1] + xv[2] + xv[3];
  float s2 = xv[0]*xv[0] + xv[1]*xv[1] + xv[2]*xv[2] + xv[3]*xv[3];
  for (int m = 1; m < 64; m <<= 1) { s += __shfl_xor(s, m); s2 += __shfl_xor(s2, m); }
  __shared__ float red[8];
  int w = tid >> 6;
  if ((tid & 63) == 0) { red[w * 2] = s; red[w * 2 + 1] = s2; }
  __syncthreads();
  s = red[0] + red[2] + red[4] + red[6];
  s2 = red[1] + red[3] + red[5] + red[7];
  float mu = s * (1.f / 1024.f);
  float var = s2 * (1.f / 1024.f) - mu * mu;
  float rs = rsqrtf(var + 1e-5f);
  f32x4 gv = *(const f32x4*)(g + tid * 4);
  f32x4 bv = *(const f32x4*)(bta + tid * 4);
  f32x4 o; u16x4 ob;
  for (int i = 0; i < 4; ++i) { o[i] = (xv[i] - mu) * rs * gv[i] + bv[i]; ob[i] = f2bf(o[i]); }
  *(f32x4*)(outf + base) = o;
  *(u16x4*)(outbf + base) = ob;
}

// ---------------------------------------------------------------- QKV (shared 64x64 weight per head)
__global__ __launch_bounds__(256) void qkv_kernel(const unsigned short* __restrict__ hbf,
    const float* __restrict__ wq, const float* __restrict__ wk, const float* __restrict__ wv,
    unsigned short* __restrict__ q, unsigned short* __restrict__ k, unsigned short* __restrict__ v) {
  __shared__ float Wt[3][64 * 65];            // transposed [d][e], pad 65: conflict-free
  int tid = threadIdx.x;
  for (int j = 0; j < 16; ++j) {
    int idx = tid + 256 * j; int e = idx >> 6, d = idx & 63;
    Wt[0][d * 65 + e] = wq[idx];
    Wt[1][d * 65 + e] = wk[idx];
    Wt[2][d * 65 + e] = wv[idx];
  }
  __syncthreads();
  int lane = tid & 63, w = tid >> 6;
  for (int it = 0; it < 8; ++it) {
    int th = blockIdx.x * 32 + w * 8 + it;    // token-head in [0, 32768)
    int t = th >> 4, hh = th & 15;
    size_t off = (size_t)t * 1024 + hh * 64;
    float xv = bf2f(hbf[off + lane]);
    float aq = 0.f, ak = 0.f, av = 0.f;
    for (int d = 0; d < 64; ++d) {
      float xd = __shfl(xv, d);
      aq = fmaf(Wt[0][d * 65 + lane], xd, aq);
      ak = fmaf(Wt[1][d * 65 + lane], xd, ak);
      av = fmaf(Wt[2][d * 65 + lane], xd, av);
    }
    q[off + lane] = f2bf(aq);
    k[off + lane] = f2bf(ak);
    v[off + lane] = f2bf(av);
  }
}

// ---------------------------------------------------------------- V transpose: [b,s,h,e] -> [b,h,e,s]
__global__ __launch_bounds__(256) void vtrans_kernel(const unsigned short* __restrict__ v,
                                                     unsigned short* __restrict__ vt) {
  __shared__ unsigned short T[64 * 72];
  int tid = threadIdx.x, st = blockIdx.x, bh = blockIdx.y;
  int b = bh >> 4, hh = bh & 15;
  for (int j = 0; j < 2; ++j) {
    int idx = tid + 256 * j; int s = idx >> 3, e0 = (idx & 7) * 8;
    u16x8 r = *(const u16x8*)(v + ((size_t)(b * 1024 + st * 64 + s) * 16 + hh) * 64 + e0);
    for (int i = 0; i < 8; ++i) T[(e0 + i) * 72 + s] = r[i];
  }
  __syncthreads();
  for (int j = 0; j < 2; ++j) {
    int idx = tid + 256 * j; int e = idx >> 3, s0 = (idx & 7) * 8;
    u16x8 r = *(const u16x8*)(&T[e * 72 + s0]);
    *(u16x8*)(vt + ((size_t)(b * 16 + hh) * 64 + e) * 1024 + st * 64 + s0) = r;
  }
}

// ---------------------------------------------------------------- flash attention
__global__ __launch_bounds__(256, 2) void attn_kernel(const unsigned short* __restrict__ qb,
    const unsigned short* __restrict__ kb, const unsigned short* __restrict__ vtb,
    unsigned short* __restrict__ ob) {
  constexpr int P = 72;                       // padded LDS stride (bf16 elems)
  __shared__ unsigned short Ks[64 * P], Vs[64 * P], Ps[4][16 * P];
  int tid = threadIdx.x, lane = tid & 63, w = tid >> 6;
  int l15 = lane & 15, lg = lane >> 4;
  int qt = blockIdx.x, bh = blockIdx.y, b = bh >> 4, hh = bh & 15;
  int q0 = qt * 64 + w * 16;
  const unsigned short* qrow = qb + ((size_t)(b * 1024 + q0 + l15) * 16 + hh) * 64 + lg * 8;
  bf16x8 qa0 = asbf(*(const u16x8*)qrow);
  bf16x8 qa1 = asbf(*(const u16x8*)(qrow + 32));
  float m_[4] = {-1e30f, -1e30f, -1e30f, -1e30f};
  float ls[4] = {0.f, 0.f, 0.f, 0.f};
  f32x4 oacc[4] = {};
  const float inv = 1.f / 32.f;
  for (int kt = 0; kt < 16; ++kt) {
    for (int j = 0; j < 2; ++j) {
      int idx = tid + 256 * j; int r = idx >> 3, c0 = (idx & 7) * 8;
      *(u16x8*)(&Ks[r * P + c0]) =
          *(const u16x8*)(kb + ((size_t)(b * 1024 + kt * 64 + r) * 16 + hh) * 64 + c0);
      *(u16x8*)(&Vs[r * P + c0]) =
          *(const u16x8*)(vtb + ((size_t)(b * 16 + hh) * 64 + r) * 1024 + kt * 64 + c0);
    }
    __syncthreads();
    f32x4 sf[4] = {};
    for (int n = 0; n < 4; ++n) {
      bf16x8 k0 = asbf(*(const u16x8*)(&Ks[(n * 16 + l15) * P + lg * 8]));
      bf16x8 k1 = asbf(*(const u16x8*)(&Ks[(n * 16 + l15) * P + 32 + lg * 8]));
      sf[n] = __builtin_amdgcn_mfma_f32_16x16x32_bf16(qa0, k0, sf[n], 0, 0, 0);
      sf[n] = __builtin_amdgcn_mfma_f32_16x16x32_bf16(qa1, k1, sf[n], 0, 0, 0);
    }
    for (int n = 0; n < 4; ++n) sf[n] *= inv;
    float mx[4], sc[4];
    for (int r = 0; r < 4; ++r) {
      float t0 = fmaxf(fmaxf(sf[0][r], sf[1][r]), fmaxf(sf[2][r], sf[3][r]));
      for (int msk = 1; msk < 16; msk <<= 1) t0 = fmaxf(t0, __shfl_xor(t0, msk));
      mx[r] = fmaxf(m_[r], t0);
      sc[r] = __expf(m_[r] - mx[r]);
      m_[r] = mx[r];
    }
    float rsum[4] = {0.f, 0.f, 0.f, 0.f};
    unsigned short pb[4][4];
    for (int n = 0; n < 4; ++n)
      for (int r = 0; r < 4; ++r) {
        float pv = __expf(sf[n][r] - mx[r]);
        rsum[r] += pv;
        pb[n][r] = f2bf(pv);
      }
    for (int r = 0; r < 4; ++r) {
      float t0 = rsum[r];
      for (int msk = 1; msk < 16; msk <<= 1) t0 += __shfl_xor(t0, msk);
      ls[r] = ls[r] * sc[r] + t0;
    }
    for (int n = 0; n < 4; ++n)
      for (int r = 0; r < 4; ++r) oacc[n][r] *= sc[r];
    unsigned short* pw = Ps[w];                // per-wave region: no barrier needed
    for (int n = 0; n < 4; ++n)
      for (int r = 0; r < 4; ++r)
        pw[(4 * lg + r) * P + n * 16 + l15] = pb[n][r];
    asm volatile("s_waitcnt lgkmcnt(0)" ::: "memory");
    bf16x8 pa0 = asbf(*(const u16x8*)(&pw[l15 * P + lg * 8]));
    bf16x8 pa1 = asbf(*(const u16x8*)(&pw[l15 * P + 32 + lg * 8]));
    for (int n = 0; n < 4; ++n) {
      bf16x8 v0 = asbf(*(const u16x8*)(&Vs[(n * 16 + l15) * P + lg * 8]));
      bf16x8 v1 = asbf(*(const u16x8*)(&Vs[(n * 16 + l15) * P + 32 + lg * 8]));
      oacc[n] = __builtin_amdgcn_mfma_f32_16x16x32_bf16(pa0, v0, oacc[n], 0, 0, 0);
      oacc[n] = __builtin_amdgcn_mfma_f32_16x16x32_bf16(pa1, v1, oacc[n], 0, 0, 0);
    }
    __syncthreads();
  }
  for (int n = 0; n < 4; ++n)
    for (int r = 0; r < 4; ++r) {
      float o = oacc[n][r] / ls[r];
      ob[((size_t)(b * 1024 + q0 + 4 * lg + r) * 16 + hh) * 64 + n * 16 + l15] = f2bf(o);
    }
}

// ---------------------------------------------------------------- bf16 GEMM, m97 structure (layer GEMMs)
template <int BM, int KSPLIT, int EPI>
__global__ __launch_bounds__(256) void gemm_kernel(
    const unsigned short* __restrict__ A, int lda,
    const unsigned short* __restrict__ B, int ldb,
    const float* __restrict__ bias,
    float* __restrict__ CfA, float* __restrict__ CfB, unsigned short* __restrict__ Cb,
    int ldc, int Ksub) {
  constexpr int LOGMT = (BM == 128) ? 4 : 5;  // M = 2048 always
  constexpr int MT = 2048 / BM;
  constexpr int MI = BM / 32;                 // A-frags per wave
  __shared__ alignas(16) char smem[33280];    // max(stage 32KB, Cs 64*130*4)
  unsigned short* As = (unsigned short*)smem;           // [2][BM*32]
  unsigned short* Bs = As + 2 * BM * 32;                // [2][128*32]
  float* Cs = (float*)smem;                             // epilogue bounce, stride 130

  int wg = blockIdx.x;
  int mt = wg & (MT - 1);
  int rest = wg >> LOGMT;
  int nt, kh;
  if (KSPLIT == 2) { nt = rest & 7; kh = rest >> 3; }   // NT must be 8 when split
  else { nt = rest; kh = 0; }
  int m0 = mt * BM, n0 = nt * 128;
  const unsigned short* Ae = A + (KSPLIT == 2 ? (size_t)kh * Ksub : 0);
  const unsigned short* Be = B + (KSPLIT == 2 ? (size_t)kh * Ksub : 0);

  int tid = threadIdx.x, ln = tid & 63, wv = tid >> 6;
  int l15 = ln & 15, lg = ln >> 4;
  int wm = (wv >> 1) * (BM / 2), wn = (wv & 1) * 64;

  auto stage = [&](int buf, int k0) {
    for (int j = 0; j < BM / 64; ++j) {
      int row = j * 64 + wv * 16 + (ln >> 2);
      gload16(Ae + (size_t)(m0 + row) * lda + k0 + (ln & 3) * 8,
              &As[buf * (BM * 32) + (j * 64 + wv * 16) * 32]);
    }
    for (int j = 0; j < 2; ++j) {
      int row = j * 64 + wv * 16 + (ln >> 2);
      gload16(Be + (size_t)(n0 + row) * ldb + k0 + (ln & 3) * 8,
              &Bs[buf * 4096 + (j * 64 + wv * 16) * 32]);
    }
  };

  f32x4 acc[MI][4] = {};
  auto compute = [&](int buf) {
    const unsigned short* as = &As[buf * (BM * 32)];
    const unsigned short* bs = &Bs[buf * 4096];
    bf16x8 af[MI], bfn[4];
    for (int mi = 0; mi < MI; ++mi)
      af[mi] = asbf(*(const u16x8*)&as[(wm + mi * 16 + l15) * 32 + lg * 8]);
    for (int ni = 0; ni < 4; ++ni)
      bfn[ni] = asbf(*(const u16x8*)&bs[(wn + ni * 16 + l15) * 32 + lg * 8]);
    for (int mi = 0; mi < MI; ++mi)
      for (int ni = 0; ni < 4; ++ni)
        acc[mi][ni] = __builtin_amdgcn_mfma_f32_16x16x32_bf16(af[mi], bfn[ni], acc[mi][ni], 0, 0, 0);
  };

  stage(0, 0);
  __syncthreads();
  int ntk = Ksub >> 5, cur = 0;
  for (int t = 0; t < ntk - 1; ++t) {
    stage(cur ^ 1, (t + 1) << 5);
    compute(cur);
    __syncthreads();
    cur ^= 1;
  }
  compute(cur);

  float* Cf = (kh == 0) ? CfA : CfB;
  const bool addb = (kh == 0);
  for (int p = 0; p < BM / 64; ++p) {
    __syncthreads();
    if ((wm >> 6) == p) {
      int rb = wm & 63;
      for (int mi = 0; mi < MI; ++mi)
        for (int ni = 0; ni < 4; ++ni) {
          int cn = wn + ni * 16 + l15;
          float bv = addb ? bias[n0 + cn] : 0.f;
          for (int r = 0; r < 4; ++r) {
            float vv = acc[mi][ni][r] + bv;
            if (EPI == 1) vv = 0.5f * vv * (1.f + erff(vv * 0.70710678118f));
            Cs[(rb + mi * 16 + 4 * lg + r) * 130 + cn] = vv;
          }
        }
    }
    __syncthreads();
    int row = tid >> 3;
    for (int ri = 0; ri < 2; ++ri) {
      int lr = ri * 32 + row;
      size_t gbase = (size_t)(m0 + p * 64 + lr) * ldc + n0;
      if (EPI == 0) {
        int c4 = (tid & 7) * 4;
        for (int j = 0; j < 4; ++j)
          *(f32x4*)(Cf + gbase + c4 + j * 32) = *(const f32x4*)&Cs[lr * 130 + c4 + j * 32];
      } else {
        for (int j = 0; j < 2; ++j) {
          int cc = (tid & 7) * 8 + j * 64;
          f32x4 v0 = *(const f32x4*)&Cs[lr * 130 + cc];
          f32x4 v1 = *(const f32x4*)&Cs[lr * 130 + cc + 4];
          u16x8 o;
          for (int i = 0; i < 4; ++i) { o[i] = f2bf(v0[i]); o[i + 4] = f2bf(v1[i]); }
          *(u16x8*)(Cb + gbase + cc) = o;
        }
      }
    }
  }
}

// ---------------------------------------------------------------- 256x256 BK=64 4-phase GEMM (logits)
// C = A @ B^T + bias. A:[2048,K] bf16, B:[N,K] bf16, C f32. grid = 8*(N/256), 512 thr.
// LDS 128 KiB: A[2][256][64] @0, B[2][256][64] @32768 elems. Swizzle blk ^= row&7 (8x16B blocks,
// balanced banks). Frag reuse: P1{B01,A03}, P2{B23}, P3{A47}, P4{none}; 8 gloads at P1 for kk+1,
// single vmcnt(0) at P4 (~3 phases of slack).
__global__ __launch_bounds__(512, 1) void gemm256_kernel(
    const unsigned short* __restrict__ A, int lda,
    const unsigned short* __restrict__ B, int ldb,
    const float* __restrict__ bias, float* __restrict__ C, int ldc, int K) {
  extern __shared__ unsigned short sm[];      // 65536 elems = 128 KiB
  int b = blockIdx.x;
  int c = (int)gridDim.x >> 3;
  int wg = (b & 7) * c + (b >> 3);            // XCD-contiguous
  int mt = wg & 7, nt = wg >> 3;
  int m0 = mt * 256, n0 = nt * 256;

  int tid = threadIdx.x, ln = tid & 63, wv = tid >> 6;
  int l15 = ln & 15, lg = ln >> 4;
  int wm = wv >> 2, wn = wv & 3;              // 2M x 4N waves; wave tile 128x64
  int l7 = l15 & 7;

  // staging: gload g covers dest rows g*64..+63; lane row = tid>>3, dest blk = tid&7,
  // source col-block pre-inverse-swizzled
  int srow = tid >> 3, sblk = (tid & 7) ^ (srow & 7);
  const unsigned short* Ab = A + (size_t)(m0 + srow) * lda + sblk * 8;
  const unsigned short* Bb = B + (size_t)(n0 + srow) * ldb + sblk * 8;
  auto stageA = [&](int e, int k0) {
#pragma unroll
    for (int g = 0; g < 4; ++g)
      gload16(Ab + ((size_t)g * 64) * lda + k0, &sm[e * 16384 + g * 4096 + wv * 512]);
  };
  auto stageB = [&](int e, int k0) {
#pragma unroll
    for (int g = 0; g < 4; ++g)
      gload16(Bb + ((size_t)g * 64) * ldb + k0, &sm[32768 + e * 16384 + g * 4096 + wv * 512]);
  };

  auto ldsA = [&](int d, int mi, int ks) -> bf16x8 {
    int row = wm * 128 + mi * 16 + l15;
    return asbf(*(const u16x8*)&sm[d * 16384 + row * 64 + (((ks << 2) | lg) ^ l7) * 8]);
  };
  auto ldsB = [&](int d, int ni, int ks) -> bf16x8 {
    int row = wn * 64 + ni * 16 + l15;
    return asbf(*(const u16x8*)&sm[32768 + d * 16384 + row * 64 + (((ks << 2) | lg) ^ l7) * 8]);
  };

  f32x4 acc[8][4] = {};
  bf16x8 Af[4][2], Bf01[2][2], Bf23[2][2];

#define PH_OPEN() __builtin_amdgcn_s_barrier(); \
  asm volatile("s_waitcnt lgkmcnt(0)" ::: "memory"); \
  __builtin_amdgcn_sched_barrier(0); __builtin_amdgcn_s_setprio(1)
#define PH_CLOSE() __builtin_amdgcn_s_setprio(0); __builtin_amdgcn_sched_barrier(0); \
  __builtin_amdgcn_s_barrier()

  // prologue: stage tile 0 into buf 0
  stageA(0, 0); stageB(0, 0);
  asm volatile("s_waitcnt vmcnt(0)" ::: "memory");
  __builtin_amdgcn_s_barrier();

  int ntk = K >> 6;
  for (int kk = 0; kk < ntk; ++kk) {
    int d = kk & 1, e = d ^ 1, k1 = (kk + 1) << 6;
    bool pf = (kk + 1 < ntk);
    { // P1: reads B ni0-1 + A mi0-3 (12); stage all 8 gloads for kk+1; MFMA Q(mi0-3 x ni0-1)
#pragma unroll
      for (int ni = 0; ni < 2; ++ni) { Bf01[ni][0] = ldsB(d, ni, 0); Bf01[ni][1] = ldsB(d, ni, 1); }
#pragma unroll
      for (int mi = 0; mi < 4; ++mi) { Af[mi][0] = ldsA(d, mi, 0); Af[mi][1] = ldsA(d, mi, 1); }
      if (pf) { stageA(e, k1); stageB(e, k1); }
      PH_OPEN();
#pragma unroll
      for (int mi = 0; mi < 4; ++mi)
#pragma unroll
        for (int ni = 0; ni < 2; ++ni) {
          acc[mi][ni] = __builtin_amdgcn_mfma_f32_16x16x32_bf16(Af[mi][0], Bf01[ni][0], acc[mi][ni], 0, 0, 0);
          acc[mi][ni] = __builtin_amdgcn_mfma_f32_16x16x32_bf16(Af[mi][1], Bf01[ni][1], acc[mi][ni], 0, 0, 0);
        }
      PH_CLOSE();
    }
    { // P2: reads B ni2-3 (4); MFMA Q(mi0-3 x ni2-3), A reused
#pragma unroll
      for (int ni = 0; ni < 2; ++ni) { Bf23[ni][0] = ldsB(d, 2 + ni, 0); Bf23[ni][1] = ldsB(d, 2 + ni, 1); }
      PH_OPEN();
#pragma unroll
      for (int mi = 0; mi < 4; ++mi)
#pragma unroll
        for (int ni = 0; ni < 2; ++ni) {
          acc[mi][2 + ni] = __builtin_amdgcn_mfma_f32_16x16x32_bf16(Af[mi][0], Bf23[ni][0], acc[mi][2 + ni], 0, 0, 0);
          acc[mi][2 + ni] = __builtin_amdgcn_mfma_f32_16x16x32_bf16(Af[mi][1], Bf23[ni][1], acc[mi][2 + ni], 0, 0, 0);
        }
      PH_CLOSE();
    }
    { // P3: reads A mi4-7 (8); MFMA Q(mi4-7 x ni2-3), B23 reused
#pragma unroll
      for (int mi = 0; mi < 4; ++mi) { Af[mi][0] = ldsA(d, 4 + mi, 0); Af[mi][1] = ldsA(d, 4 + mi, 1); }
      PH_OPEN();
#pragma unroll
      for (int mi = 0; mi < 4; ++mi)
#pragma unroll
        for (int ni = 0; ni < 2; ++ni) {
          acc[4 + mi][2 + ni] = __builtin_amdgcn_mfma_f32_16x16x32_bf16(Af[mi][0], Bf23[ni][0], acc[4 + mi][2 + ni], 0, 0, 0);
          acc[4 + mi][2 + ni] = __builtin_amdgcn_mfma_f32_16x16x32_bf16(Af[mi][1], Bf23[ni][1], acc[4 + mi][2 + ni], 0, 0, 0);
        }
      PH_CLOSE();
    }
    { // P4: no reads; wait kk+1 staged (issued 3 phases ago); MFMA Q(mi4-7 x ni0-1), B01 reused
      asm volatile("s_waitcnt vmcnt(0)" ::: "memory");
      __builtin_amdgcn_s_barrier();
      __builtin_amdgcn_s_setprio(1);
#pragma unroll
      for (int mi = 0; mi < 4; ++mi)
#pragma unroll
        for (int ni = 0; ni < 2; ++ni) {
          acc[4 + mi][ni] = __builtin_amdgcn_mfma_f32_16x16x32_bf16(Af[mi][0], Bf01[ni][0], acc[4 + mi][ni], 0, 0, 0);
          acc[4 + mi][ni] = __builtin_amdgcn_mfma_f32_16x16x32_bf16(Af[mi][1], Bf01[ni][1], acc[4 + mi][ni], 0, 0, 0);
        }
      PH_CLOSE();
    }
  }
#undef PH_OPEN
#undef PH_CLOSE

  // epilogue: bias + direct stores
#pragma unroll
  for (int ni = 0; ni < 4; ++ni) {
    int col = n0 + wn * 64 + ni * 16 + l15;
    float bv = bias[col];
#pragma unroll
    for (int mi = 0; mi < 8; ++mi) {
      int row = m0 + wm * 128 + mi * 16 + lg * 4;
#pragma unroll
      for (int r = 0; r < 4; ++r)
        C[(size_t)(row + r) * ldc + col] = acc[mi][ni][r] + bv;
    }
  }
}

// ----------------------------------------------------------------
extern "C" void kernel_launch(void* const* d_in, const int* in_sizes, int n_in,
                              void* d_out, int out_size, void* d_ws, size_t ws_size,
                              hipStream_t stream) {
  const int* x = (const int*)d_in[0];
  const float* tok = (const float*)d_in[1];
  const float* pos = (const float*)d_in[2];
  const float* wq = (const float*)d_in[3];
  const float* wk = (const float*)d_in[4];
  const float* wv = (const float*)d_in[5];
  const float* wo = (const float*)d_in[6];
  const float* bo = (const float*)d_in[7];
  const float* ln1g = (const float*)d_in[8];
  const float* ln1b = (const float*)d_in[9];
  const float* ln2g = (const float*)d_in[10];
  const float* ln2b = (const float*)d_in[11];
  const float* w1 = (const float*)d_in[12];
  const float* b1 = (const float*)d_in[13];
  const float* w2 = (const float*)d_in[14];
  const float* b2 = (const float*)d_in[15];
  const float* outw = (const float*)d_in[16];
  const float* outb = (const float*)d_in[17];
  float* out = (float*)d_out;

  const size_t MiB = 1 << 20;
  const size_t need = 4 * MiB + 65536000;
  if (ws_size < need) return;
  char* base = (char*)d_ws;
  unsigned short* hbf = (unsigned short*)base;            // 4 MiB, persistent
  char* R = base + 4 * MiB;
  float* hf  = (float*)(R);                               // 8 MiB
  float* x1f = (float*)(R + 8 * MiB);                     // 8 MiB
  unsigned short* x1bf = (unsigned short*)(R + 16 * MiB); // 4 MiB
  float* cfA = (float*)(R + 20 * MiB);                    // 8 MiB
  float* cfB = (float*)(R + 28 * MiB);                    // 8 MiB
  unsigned short* qs = (unsigned short*)(R + 36 * MiB);   // 6 slots x 4 MiB
  const size_t SL = 2048ull * 1024;
  unsigned short* qbf = qs;
  unsigned short* kbf = qs + SL;
  unsigned short* vbf = qs + 2 * SL;                      // also attn-out
  unsigned short* vtbf = qs + 3 * SL;                     // also wobf
  unsigned short* wobf = vtbf;
  unsigned short* w1bf = qbf;
  unsigned short* w2bf = qbf;
  unsigned short* ffbf = vbf;
  unsigned short* outwbf = (unsigned short*)R;            // 62.5 MiB, after layers

  embed_kernel<<<2048, 256, 0, stream>>>(x, tok, pos, hf, hbf);
  for (int l = 0; l < 4; ++l) {
    qkv_kernel<<<1024, 256, 0, stream>>>(hbf, wq + l * 4096, wk + l * 4096, wv + l * 4096,
                                         qbf, kbf, vbf);
    vtrans_kernel<<<dim3(16, 32), 256, 0, stream>>>(vbf, vtbf);
    attn_kernel<<<dim3(16, 32), 256, 0, stream>>>(qbf, kbf, vtbf, vbf);
    cvt_kernel<<<512, 256, 0, stream>>>(wo + (size_t)l * 1048576, wobf, 131072);
    cvt_kernel<<<2048, 256, 0, stream>>>(w1 + (size_t)l * 4194304, w1bf, 524288);
    gemm_kernel<64, 2, 0><<<512, 256, 0, stream>>>(
        vbf, 1024, wobf, 1024, bo + l * 1024, cfA, cfB, nullptr, 1024, 512);
    ln_kernel<<<2048, 256, 0, stream>>>(cfA, cfB, hf, ln1g + l * 1024, ln1b + l * 1024,
                                        x1f, x1bf);
    gemm_kernel<128, 1, 1><<<512, 256, 0, stream>>>(
        x1bf, 1024, w1bf, 1024, b1 + l * 4096, nullptr, nullptr, ffbf, 4096, 1024);
    cvt_kernel<<<2048, 256, 0, stream>>>(w2 + (size_t)l * 4194304, w2bf, 524288);
    gemm_kernel<64, 2, 0><<<512, 256, 0, stream>>>(
        ffbf, 4096, w2bf, 4096, b2 + l * 1024, cfA, cfB, nullptr, 1024, 2048);
    ln_kernel<<<2048, 256, 0, stream>>>(cfA, cfB, x1f, ln2g + l * 1024, ln2b + l * 1024,
                                        hf, hbf);
  }
  cvt_kernel<<<2048, 256, 0, stream>>>(outw, outwbf, 4096000);
  gemm256_kernel<<<1000, 512, 131072, stream>>>(hbf, 1024, outwbf, 1024, outb, out, 32000, 1024);
}

// Round 6
// 1056.527 us; speedup vs baseline: 1.0817x; 1.0817x over previous
//
#include <hip/hip_runtime.h>
#include <math.h>

typedef float f32x4 __attribute__((ext_vector_type(4)));
typedef unsigned short u16x8 __attribute__((ext_vector_type(8)));
typedef unsigned short u16x4 __attribute__((ext_vector_type(4)));
typedef __bf16 bf16x8 __attribute__((ext_vector_type(8)));
typedef unsigned int u32;

#define DEV static __device__ __forceinline__

DEV unsigned short f2bf(float f) {            // RNE f32 -> bf16 bits
  unsigned u = __float_as_uint(f);
  u += 0x7FFFu + ((u >> 16) & 1u);
  return (unsigned short)(u >> 16);
}
DEV float bf2f(unsigned short s) { return __uint_as_float(((unsigned)s) << 16); }
DEV bf16x8 asbf(u16x8 v) { return __builtin_bit_cast(bf16x8, v); }

DEV void gload16(const void* g, void* l) {    // async global->LDS, 16B/lane, wave-uniform LDS base
  __builtin_amdgcn_global_load_lds((const __attribute__((address_space(1))) u32*)g,
                                   (__attribute__((address_space(3))) u32*)l, 16, 0, 0);
}

// ---------------------------------------------------------------- f32 -> bf16 bulk convert
__global__ void cvt_kernel(const float* __restrict__ in, unsigned short* __restrict__ out, int n8) {
  for (int i = blockIdx.x * 256 + threadIdx.x; i < n8; i += gridDim.x * 256) {
    const float* s = in + (size_t)i * 8;
    f32x4 a = *(const f32x4*)s, b = *(const f32x4*)(s + 4);
    u16x8 o;
    for (int j = 0; j < 4; ++j) { o[j] = f2bf(a[j]); o[j + 4] = f2bf(b[j]); }
    *(u16x8*)(out + (size_t)i * 8) = o;
  }
}

// ---------------------------------------------------------------- embed
__global__ void embed_kernel(const int* __restrict__ x, const float* __restrict__ tok,
                             const float* __restrict__ pos, float* __restrict__ h,
                             unsigned short* __restrict__ hbf) {
  int t = blockIdx.x, tid = threadIdx.x;
  int v = x[t], s = t & 1023;                 // S = 1024
  f32x4 a = *(const f32x4*)(tok + (size_t)v * 1024 + tid * 4);
  f32x4 b = *(const f32x4*)(pos + (size_t)s * 1024 + tid * 4);
  f32x4 r = a + b;
  *(f32x4*)(h + (size_t)t * 1024 + tid * 4) = r;
  u16x4 rb;
  for (int i = 0; i < 4; ++i) rb[i] = f2bf(r[i]);
  *(u16x4*)(hbf + (size_t)t * 1024 + tid * 4) = rb;
}

// ---------------------------------------------------------------- LayerNorm(preA + preB + res)
__global__ __launch_bounds__(256) void ln_kernel(const float* __restrict__ preA,
    const float* __restrict__ preB, const float* __restrict__ res,
    const float* __restrict__ g, const float* __restrict__ bta,
    float* __restrict__ outf, unsigned short* __restrict__ outbf) {
  int row = blockIdx.x, tid = threadIdx.x;
  size_t base = (size_t)row * 1024 + tid * 4;
  f32x4 xv = *(const f32x4*)(preA + base);
  xv += *(const f32x4*)(preB + base);
  xv += *(const f32x4*)(res + base);
  float s = xv[0] + xv[1] + xv[2] + xv[3];
  float s2 = xv[0]*xv[0] + xv[1]*xv[1] + xv[2]*xv[2] + xv[3]*xv[3];
  for (int m = 1; m < 64; m <<= 1) { s += __shfl_xor(s, m); s2 += __shfl_xor(s2, m); }
  __shared__ float red[8];
  int w = tid >> 6;
  if ((tid & 63) == 0) { red[w * 2] = s; red[w * 2 + 1] = s2; }
  __syncthreads();
  s = red[0] + red[2] + red[4] + red[6];
  s2 = red[1] + red[3] + red[5] + red[7];
  float mu = s * (1.f / 1024.f);
  float var = s2 * (1.f / 1024.f) - mu * mu;
  float rs = rsqrtf(var + 1e-5f);
  f32x4 gv = *(const f32x4*)(g + tid * 4);
  f32x4 bv = *(const f32x4*)(bta + tid * 4);
  f32x4 o; u16x4 ob;
  for (int i = 0; i < 4; ++i) { o[i] = (xv[i] - mu) * rs * gv[i] + bv[i]; ob[i] = f2bf(o[i]); }
  *(f32x4*)(outf + base) = o;
  *(u16x4*)(outbf + base) = ob;
}

// ---------------------------------------------------------------- QKV (shared 64x64 weight per head)
__global__ __launch_bounds__(256) void qkv_kernel(const unsigned short* __restrict__ hbf,
    const float* __restrict__ wq, const float* __restrict__ wk, const float* __restrict__ wv,
    unsigned short* __restrict__ q, unsigned short* __restrict__ k, unsigned short* __restrict__ v) {
  __shared__ float Wt[3][64 * 65];            // transposed [d][e], pad 65: conflict-free
  int tid = threadIdx.x;
  for (int j = 0; j < 16; ++j) {
    int idx = tid + 256 * j; int e = idx >> 6, d = idx & 63;
    Wt[0][d * 65 + e] = wq[idx];
    Wt[1][d * 65 + e] = wk[idx];
    Wt[2][d * 65 + e] = wv[idx];
  }
  __syncthreads();
  int lane = tid & 63, w = tid >> 6;
  for (int it = 0; it < 8; ++it) {
    int th = blockIdx.x * 32 + w * 8 + it;    // token-head in [0, 32768)
    int t = th >> 4, hh = th & 15;
    size_t off = (size_t)t * 1024 + hh * 64;
    float xv = bf2f(hbf[off + lane]);
    float aq = 0.f, ak = 0.f, av = 0.f;
    for (int d = 0; d < 64; ++d) {
      float xd = __shfl(xv, d);
      aq = fmaf(Wt[0][d * 65 + lane], xd, aq);
      ak = fmaf(Wt[1][d * 65 + lane], xd, ak);
      av = fmaf(Wt[2][d * 65 + lane], xd, av);
    }
    q[off + lane] = f2bf(aq);
    k[off + lane] = f2bf(ak);
    v[off + lane] = f2bf(av);
  }
}

// ---------------------------------------------------------------- V transpose: [b,s,h,e] -> [b,h,e,s]
__global__ __launch_bounds__(256) void vtrans_kernel(const unsigned short* __restrict__ v,
                                                     unsigned short* __restrict__ vt) {
  __shared__ unsigned short T[64 * 72];
  int tid = threadIdx.x, st = blockIdx.x, bh = blockIdx.y;
  int b = bh >> 4, hh = bh & 15;
  for (int j = 0; j < 2; ++j) {
    int idx = tid + 256 * j; int s = idx >> 3, e0 = (idx & 7) * 8;
    u16x8 r = *(const u16x8*)(v + ((size_t)(b * 1024 + st * 64 + s) * 16 + hh) * 64 + e0);
    for (int i = 0; i < 8; ++i) T[(e0 + i) * 72 + s] = r[i];
  }
  __syncthreads();
  for (int j = 0; j < 2; ++j) {
    int idx = tid + 256 * j; int e = idx >> 3, s0 = (idx & 7) * 8;
    u16x8 r = *(const u16x8*)(&T[e * 72 + s0]);
    *(u16x8*)(vt + ((size_t)(b * 16 + hh) * 64 + e) * 1024 + st * 64 + s0) = r;
  }
}

// ---------------------------------------------------------------- flash attention, KVBLK=128
__global__ __launch_bounds__(256, 2) void attn_kernel(const unsigned short* __restrict__ qb,
    const unsigned short* __restrict__ kb, const unsigned short* __restrict__ vtb,
    unsigned short* __restrict__ ob) {
  constexpr int PK = 72, PV = 136, PP = 136;
  __shared__ unsigned short Ks[128 * PK], Vs[64 * PV], Ps[4][16 * PP];
  int tid = threadIdx.x, lane = tid & 63, w = tid >> 6;
  int l15 = lane & 15, lg = lane >> 4;
  int qt = blockIdx.x, bh = blockIdx.y, b = bh >> 4, hh = bh & 15;
  int q0 = qt * 64 + w * 16;
  const unsigned short* qrow = qb + ((size_t)(b * 1024 + q0 + l15) * 16 + hh) * 64 + lg * 8;
  bf16x8 qa0 = asbf(*(const u16x8*)qrow);
  bf16x8 qa1 = asbf(*(const u16x8*)(qrow + 32));
  float m_[4] = {-1e30f, -1e30f, -1e30f, -1e30f};
  float ls[4] = {0.f, 0.f, 0.f, 0.f};
  f32x4 oacc[4] = {};
  const float inv = 1.f / 32.f;
  for (int kt = 0; kt < 8; ++kt) {
    for (int j = 0; j < 4; ++j) {
      int idx = tid + 256 * j;                // 1024 vec-slots
      int r = idx >> 3, c0 = (idx & 7) * 8;   // K: 128 rows x 8 col-blocks
      *(u16x8*)(&Ks[r * PK + c0]) =
          *(const u16x8*)(kb + ((size_t)(b * 1024 + kt * 128 + r) * 16 + hh) * 64 + c0);
      int rv = idx >> 4, cv = (idx & 15) * 8; // V^T: 64 e-rows x 16 s-blocks
      *(u16x8*)(&Vs[rv * PV + cv]) =
          *(const u16x8*)(vtb + ((size_t)((b * 16 + hh) * 64) + rv) * 1024 + kt * 128 + cv);
    }
    __syncthreads();
    f32x4 sf[8] = {};
#pragma unroll
    for (int n = 0; n < 8; ++n) {
      bf16x8 k0 = asbf(*(const u16x8*)(&Ks[(n * 16 + l15) * PK + lg * 8]));
      bf16x8 k1 = asbf(*(const u16x8*)(&Ks[(n * 16 + l15) * PK + 32 + lg * 8]));
      sf[n] = __builtin_amdgcn_mfma_f32_16x16x32_bf16(qa0, k0, sf[n], 0, 0, 0);
      sf[n] = __builtin_amdgcn_mfma_f32_16x16x32_bf16(qa1, k1, sf[n], 0, 0, 0);
    }
#pragma unroll
    for (int n = 0; n < 8; ++n) sf[n] *= inv;
    float mx[4], sc[4];
#pragma unroll
    for (int r = 0; r < 4; ++r) {
      float t0 = fmaxf(fmaxf(fmaxf(sf[0][r], sf[1][r]), fmaxf(sf[2][r], sf[3][r])),
                       fmaxf(fmaxf(sf[4][r], sf[5][r]), fmaxf(sf[6][r], sf[7][r])));
      for (int msk = 1; msk < 16; msk <<= 1) t0 = fmaxf(t0, __shfl_xor(t0, msk));
      mx[r] = fmaxf(m_[r], t0);
      sc[r] = __expf(m_[r] - mx[r]);
      m_[r] = mx[r];
    }
    float rsum[4] = {0.f, 0.f, 0.f, 0.f};
    unsigned short pb[8][4];
#pragma unroll
    for (int n = 0; n < 8; ++n)
#pragma unroll
      for (int r = 0; r < 4; ++r) {
        float pv = __expf(sf[n][r] - mx[r]);
        rsum[r] += pv;
        pb[n][r] = f2bf(pv);
      }
#pragma unroll
    for (int r = 0; r < 4; ++r) {
      float t0 = rsum[r];
      for (int msk = 1; msk < 16; msk <<= 1) t0 += __shfl_xor(t0, msk);
      ls[r] = ls[r] * sc[r] + t0;
    }
#pragma unroll
    for (int n = 0; n < 4; ++n)
#pragma unroll
      for (int r = 0; r < 4; ++r) oacc[n][r] *= sc[r];
    unsigned short* pw = Ps[w];                // per-wave region: no block barrier needed
#pragma unroll
    for (int n = 0; n < 8; ++n)
#pragma unroll
      for (int r = 0; r < 4; ++r)
        pw[(4 * lg + r) * PP + n * 16 + l15] = pb[n][r];
    asm volatile("s_waitcnt lgkmcnt(0)" ::: "memory");
    __builtin_amdgcn_sched_barrier(0);
    bf16x8 pa[4];
#pragma unroll
    for (int ks = 0; ks < 4; ++ks)
      pa[ks] = asbf(*(const u16x8*)(&pw[l15 * PP + ks * 32 + lg * 8]));
#pragma unroll
    for (int n = 0; n < 4; ++n) {
#pragma unroll
      for (int ks = 0; ks < 4; ++ks) {
        bf16x8 v0 = asbf(*(const u16x8*)(&Vs[(n * 16 + l15) * PV + ks * 32 + lg * 8]));
        oacc[n] = __builtin_amdgcn_mfma_f32_16x16x32_bf16(pa[ks], v0, oacc[n], 0, 0, 0);
      }
    }
    __syncthreads();
  }
#pragma unroll
  for (int n = 0; n < 4; ++n)
#pragma unroll
    for (int r = 0; r < 4; ++r) {
      float o = oacc[n][r] / ls[r];
      ob[((size_t)(b * 1024 + q0 + 4 * lg + r) * 16 + hh) * 64 + n * 16 + l15] = f2bf(o);
    }
}

// ---------------------------------------------------------------- bf16 GEMM, m97 structure (layer GEMMs)
template <int BM, int KSPLIT, int EPI>
__global__ __launch_bounds__(256) void gemm_kernel(
    const unsigned short* __restrict__ A, int lda,
    const unsigned short* __restrict__ B, int ldb,
    const float* __restrict__ bias,
    float* __restrict__ CfA, float* __restrict__ CfB, unsigned short* __restrict__ Cb,
    int ldc, int Ksub) {
  constexpr int LOGMT = (BM == 128) ? 4 : 5;  // M = 2048 always
  constexpr int MT = 2048 / BM;
  constexpr int MI = BM / 32;                 // A-frags per wave
  __shared__ alignas(16) char smem[33280];    // max(stage 32KB, Cs 64*130*4)
  unsigned short* As = (unsigned short*)smem;           // [2][BM*32]
  unsigned short* Bs = As + 2 * BM * 32;                // [2][128*32]
  float* Cs = (float*)smem;                             // epilogue bounce, stride 130

  int wg = blockIdx.x;
  int mt = wg & (MT - 1);
  int rest = wg >> LOGMT;
  int nt, kh;
  if (KSPLIT == 2) { nt = rest & 7; kh = rest >> 3; }   // NT must be 8 when split
  else { nt = rest; kh = 0; }
  int m0 = mt * BM, n0 = nt * 128;
  const unsigned short* Ae = A + (KSPLIT == 2 ? (size_t)kh * Ksub : 0);
  const unsigned short* Be = B + (KSPLIT == 2 ? (size_t)kh * Ksub : 0);

  int tid = threadIdx.x, ln = tid & 63, wv = tid >> 6;
  int l15 = ln & 15, lg = ln >> 4;
  int wm = (wv >> 1) * (BM / 2), wn = (wv & 1) * 64;

  auto stage = [&](int buf, int k0) {
    for (int j = 0; j < BM / 64; ++j) {
      int row = j * 64 + wv * 16 + (ln >> 2);
      gload16(Ae + (size_t)(m0 + row) * lda + k0 + (ln & 3) * 8,
              &As[buf * (BM * 32) + (j * 64 + wv * 16) * 32]);
    }
    for (int j = 0; j < 2; ++j) {
      int row = j * 64 + wv * 16 + (ln >> 2);
      gload16(Be + (size_t)(n0 + row) * ldb + k0 + (ln & 3) * 8,
              &Bs[buf * 4096 + (j * 64 + wv * 16) * 32]);
    }
  };

  f32x4 acc[MI][4] = {};
  auto compute = [&](int buf) {
    const unsigned short* as = &As[buf * (BM * 32)];
    const unsigned short* bs = &Bs[buf * 4096];
    bf16x8 af[MI], bfn[4];
    for (int mi = 0; mi < MI; ++mi)
      af[mi] = asbf(*(const u16x8*)&as[(wm + mi * 16 + l15) * 32 + lg * 8]);
    for (int ni = 0; ni < 4; ++ni)
      bfn[ni] = asbf(*(const u16x8*)&bs[(wn + ni * 16 + l15) * 32 + lg * 8]);
    for (int mi = 0; mi < MI; ++mi)
      for (int ni = 0; ni < 4; ++ni)
        acc[mi][ni] = __builtin_amdgcn_mfma_f32_16x16x32_bf16(af[mi], bfn[ni], acc[mi][ni], 0, 0, 0);
  };

  stage(0, 0);
  __syncthreads();
  int ntk = Ksub >> 5, cur = 0;
  for (int t = 0; t < ntk - 1; ++t) {
    stage(cur ^ 1, (t + 1) << 5);
    compute(cur);
    __syncthreads();
    cur ^= 1;
  }
  compute(cur);

  float* Cf = (kh == 0) ? CfA : CfB;
  const bool addb = (kh == 0);
  for (int p = 0; p < BM / 64; ++p) {
    __syncthreads();
    if ((wm >> 6) == p) {
      int rb = wm & 63;
      for (int mi = 0; mi < MI; ++mi)
        for (int ni = 0; ni < 4; ++ni) {
          int cn = wn + ni * 16 + l15;
          float bv = addb ? bias[n0 + cn] : 0.f;
          for (int r = 0; r < 4; ++r) {
            float vv = acc[mi][ni][r] + bv;
            if (EPI == 1) vv = 0.5f * vv * (1.f + erff(vv * 0.70710678118f));
            Cs[(rb + mi * 16 + 4 * lg + r) * 130 + cn] = vv;
          }
        }
    }
    __syncthreads();
    int row = tid >> 3;
    for (int ri = 0; ri < 2; ++ri) {
      int lr = ri * 32 + row;
      size_t gbase = (size_t)(m0 + p * 64 + lr) * ldc + n0;
      if (EPI == 0) {
        int c4 = (tid & 7) * 4;
        for (int j = 0; j < 4; ++j)
          *(f32x4*)(Cf + gbase + c4 + j * 32) = *(const f32x4*)&Cs[lr * 130 + c4 + j * 32];
      } else {
        for (int j = 0; j < 2; ++j) {
          int cc = (tid & 7) * 8 + j * 64;
          f32x4 v0 = *(const f32x4*)&Cs[lr * 130 + cc];
          f32x4 v1 = *(const f32x4*)&Cs[lr * 130 + cc + 4];
          u16x8 o;
          for (int i = 0; i < 4; ++i) { o[i] = f2bf(v0[i]); o[i + 4] = f2bf(v1[i]); }
          *(u16x8*)(Cb + gbase + cc) = o;
        }
      }
    }
  }
}

// ---------------------------------------------------------------- 256x256 BK=64 4-phase GEMM (logits)
// C = A @ B^T + bias. A:[2048,K] bf16, B:[N,K] bf16, C f32. grid = 8*(N/256), 512 thr.
// K-loop unchanged from R5. NEW: LDS-bounce epilogue -> full-128B-line f32x4 stores (no RMW).
__global__ __launch_bounds__(512, 1) void gemm256_kernel(
    const unsigned short* __restrict__ A, int lda,
    const unsigned short* __restrict__ B, int ldb,
    const float* __restrict__ bias, float* __restrict__ C, int ldc, int K) {
  extern __shared__ unsigned short sm[];      // 65536 elems = 128 KiB
  int b = blockIdx.x;
  int c = (int)gridDim.x >> 3;
  int wg = (b & 7) * c + (b >> 3);            // XCD-contiguous
  int mt = wg & 7, nt = wg >> 3;
  int m0 = mt * 256, n0 = nt * 256;

  int tid = threadIdx.x, ln = tid & 63, wv = tid >> 6;
  int l15 = ln & 15, lg = ln >> 4;
  int wm = wv >> 2, wn = wv & 3;              // 2M x 4N waves; wave tile 128x64
  int l7 = l15 & 7;

  int srow = tid >> 3, sblk = (tid & 7) ^ (srow & 7);
  const unsigned short* Ab = A + (size_t)(m0 + srow) * lda + sblk * 8;
  const unsigned short* Bb = B + (size_t)(n0 + srow) * ldb + sblk * 8;
  auto stageA = [&](int e, int k0) {
#pragma unroll
    for (int g = 0; g < 4; ++g)
      gload16(Ab + ((size_t)g * 64) * lda + k0, &sm[e * 16384 + g * 4096 + wv * 512]);
  };
  auto stageB = [&](int e, int k0) {
#pragma unroll
    for (int g = 0; g < 4; ++g)
      gload16(Bb + ((size_t)g * 64) * ldb + k0, &sm[32768 + e * 16384 + g * 4096 + wv * 512]);
  };

  auto ldsA = [&](int d, int mi, int ks) -> bf16x8 {
    int row = wm * 128 + mi * 16 + l15;
    return asbf(*(const u16x8*)&sm[d * 16384 + row * 64 + (((ks << 2) | lg) ^ l7) * 8]);
  };
  auto ldsB = [&](int d, int ni, int ks) -> bf16x8 {
    int row = wn * 64 + ni * 16 + l15;
    return asbf(*(const u16x8*)&sm[32768 + d * 16384 + row * 64 + (((ks << 2) | lg) ^ l7) * 8]);
  };

  f32x4 acc[8][4] = {};
  bf16x8 Af[4][2], Bf01[2][2], Bf23[2][2];

#define PH_OPEN() __builtin_amdgcn_s_barrier(); \
  asm volatile("s_waitcnt lgkmcnt(0)" ::: "memory"); \
  __builtin_amdgcn_sched_barrier(0); __builtin_amdgcn_s_setprio(1)
#define PH_CLOSE() __builtin_amdgcn_s_setprio(0); __builtin_amdgcn_sched_barrier(0); \
  __builtin_amdgcn_s_barrier()

  stageA(0, 0); stageB(0, 0);
  asm volatile("s_waitcnt vmcnt(0)" ::: "memory");
  __builtin_amdgcn_s_barrier();

  int ntk = K >> 6;
  for (int kk = 0; kk < ntk; ++kk) {
    int d = kk & 1, e = d ^ 1, k1 = (kk + 1) << 6;
    bool pf = (kk + 1 < ntk);
    { // P1
#pragma unroll
      for (int ni = 0; ni < 2; ++ni) { Bf01[ni][0] = ldsB(d, ni, 0); Bf01[ni][1] = ldsB(d, ni, 1); }
#pragma unroll
      for (int mi = 0; mi < 4; ++mi) { Af[mi][0] = ldsA(d, mi, 0); Af[mi][1] = ldsA(d, mi, 1); }
      if (pf) { stageA(e, k1); stageB(e, k1); }
      PH_OPEN();
#pragma unroll
      for (int mi = 0; mi < 4; ++mi)
#pragma unroll
        for (int ni = 0; ni < 2; ++ni) {
          acc[mi][ni] = __builtin_amdgcn_mfma_f32_16x16x32_bf16(Af[mi][0], Bf01[ni][0], acc[mi][ni], 0, 0, 0);
          acc[mi][ni] = __builtin_amdgcn_mfma_f32_16x16x32_bf16(Af[mi][1], Bf01[ni][1], acc[mi][ni], 0, 0, 0);
        }
      PH_CLOSE();
    }
    { // P2
#pragma unroll
      for (int ni = 0; ni < 2; ++ni) { Bf23[ni][0] = ldsB(d, 2 + ni, 0); Bf23[ni][1] = ldsB(d, 2 + ni, 1); }
      PH_OPEN();
#pragma unroll
      for (int mi = 0; mi < 4; ++mi)
#pragma unroll
        for (int ni = 0; ni < 2; ++ni) {
          acc[mi][2 + ni] = __builtin_amdgcn_mfma_f32_16x16x32_bf16(Af[mi][0], Bf23[ni][0], acc[mi][2 + ni], 0, 0, 0);
          acc[mi][2 + ni] = __builtin_amdgcn_mfma_f32_16x16x32_bf16(Af[mi][1], Bf23[ni][1], acc[mi][2 + ni], 0, 0, 0);
        }
      PH_CLOSE();
    }
    { // P3
#pragma unroll
      for (int mi = 0; mi < 4; ++mi) { Af[mi][0] = ldsA(d, 4 + mi, 0); Af[mi][1] = ldsA(d, 4 + mi, 1); }
      PH_OPEN();
#pragma unroll
      for (int mi = 0; mi < 4; ++mi)
#pragma unroll
        for (int ni = 0; ni < 2; ++ni) {
          acc[4 + mi][2 + ni] = __builtin_amdgcn_mfma_f32_16x16x32_bf16(Af[mi][0], Bf23[ni][0], acc[4 + mi][2 + ni], 0, 0, 0);
          acc[4 + mi][2 + ni] = __builtin_amdgcn_mfma_f32_16x16x32_bf16(Af[mi][1], Bf23[ni][1], acc[4 + mi][2 + ni], 0, 0, 0);
        }
      PH_CLOSE();
    }
    { // P4
      asm volatile("s_waitcnt vmcnt(0)" ::: "memory");
      __builtin_amdgcn_s_barrier();
      __builtin_amdgcn_s_setprio(1);
#pragma unroll
      for (int mi = 0; mi < 4; ++mi)
#pragma unroll
        for (int ni = 0; ni < 2; ++ni) {
          acc[4 + mi][ni] = __builtin_amdgcn_mfma_f32_16x16x32_bf16(Af[mi][0], Bf01[ni][0], acc[4 + mi][ni], 0, 0, 0);
          acc[4 + mi][ni] = __builtin_amdgcn_mfma_f32_16x16x32_bf16(Af[mi][1], Bf01[ni][1], acc[4 + mi][ni], 0, 0, 0);
        }
      PH_CLOSE();
    }
  }
#undef PH_OPEN
#undef PH_CLOSE

  // ---- epilogue: LDS bounce (per-wave 64x64 f32 region), full-line f32x4 stores
  float* fb = (float*)sm;
  int fbase = wv * 4096;                      // 8 waves x 16 KiB = 128 KiB exactly
  float bv[4];
#pragma unroll
  for (int ni = 0; ni < 4; ++ni) bv[ni] = bias[n0 + wn * 64 + ni * 16 + l15];
#pragma unroll
  for (int p = 0; p < 2; ++p) {
    if (p) { asm volatile("s_waitcnt lgkmcnt(0)" ::: "memory"); __builtin_amdgcn_sched_barrier(0); }
#pragma unroll
    for (int mi = 0; mi < 4; ++mi)
#pragma unroll
      for (int ni = 0; ni < 4; ++ni)
#pragma unroll
        for (int r = 0; r < 4; ++r)
          fb[fbase + (mi * 16 + lg * 4 + r) * 64 + ni * 16 + l15] = acc[4 * p + mi][ni][r] + bv[ni];
    asm volatile("s_waitcnt lgkmcnt(0)" ::: "memory");
    __builtin_amdgcn_sched_barrier(0);
#pragma unroll
    for (int i = 0; i < 16; ++i) {
      int row = i * 4 + lg;
      f32x4 v = *(const f32x4*)&fb[fbase + row * 64 + l15 * 4];
      int grow = m0 + wm * 128 + p * 64 + row;
      *(f32x4*)(&C[(size_t)grow * ldc + n0 + wn * 64 + l15 * 4]) = v;
    }
  }
}

// ----------------------------------------------------------------
extern "C" void kernel_launch(void* const* d_in, const int* in_sizes, int n_in,
                              void* d_out, int out_size, void* d_ws, size_t ws_size,
                              hipStream_t stream) {
  const int* x = (const int*)d_in[0];
  const float* tok = (const float*)d_in[1];
  const float* pos = (const float*)d_in[2];
  const float* wq = (const float*)d_in[3];
  const float* wk = (const float*)d_in[4];
  const float* wv = (const float*)d_in[5];
  const float* wo = (const float*)d_in[6];
  const float* bo = (const float*)d_in[7];
  const float* ln1g = (const float*)d_in[8];
  const float* ln1b = (const float*)d_in[9];
  const float* ln2g = (const float*)d_in[10];
  const float* ln2b = (const float*)d_in[11];
  const float* w1 = (const float*)d_in[12];
  const float* b1 = (const float*)d_in[13];
  const float* w2 = (const float*)d_in[14];
  const float* b2 = (const float*)d_in[15];
  const float* outw = (const float*)d_in[16];
  const float* outb = (const float*)d_in[17];
  float* out = (float*)d_out;

  const size_t MiB = 1 << 20;
  const size_t need = 4 * MiB + 65536000;
  if (ws_size < need) return;
  char* base = (char*)d_ws;
  unsigned short* hbf = (unsigned short*)base;            // 4 MiB, persistent
  char* R = base + 4 * MiB;
  float* hf  = (float*)(R);                               // 8 MiB
  float* x1f = (float*)(R + 8 * MiB);                     // 8 MiB
  unsigned short* x1bf = (unsigned short*)(R + 16 * MiB); // 4 MiB
  float* cfA = (float*)(R + 20 * MiB);                    // 8 MiB
  float* cfB = (float*)(R + 28 * MiB);                    // 8 MiB
  unsigned short* qs = (unsigned short*)(R + 36 * MiB);   // 6 slots x 4 MiB
  const size_t SL = 2048ull * 1024;
  unsigned short* qbf = qs;
  unsigned short* kbf = qs + SL;
  unsigned short* vbf = qs + 2 * SL;                      // also attn-out
  unsigned short* vtbf = qs + 3 * SL;                     // also wobf
  unsigned short* wobf = vtbf;
  unsigned short* w1bf = qbf;
  unsigned short* w2bf = qbf;
  unsigned short* ffbf = vbf;
  unsigned short* outwbf = (unsigned short*)R;            // 62.5 MiB, after layers

  embed_kernel<<<2048, 256, 0, stream>>>(x, tok, pos, hf, hbf);
  for (int l = 0; l < 4; ++l) {
    qkv_kernel<<<1024, 256, 0, stream>>>(hbf, wq + l * 4096, wk + l * 4096, wv + l * 4096,
                                         qbf, kbf, vbf);
    vtrans_kernel<<<dim3(16, 32), 256, 0, stream>>>(vbf, vtbf);
    attn_kernel<<<dim3(16, 32), 256, 0, stream>>>(qbf, kbf, vtbf, vbf);
    cvt_kernel<<<512, 256, 0, stream>>>(wo + (size_t)l * 1048576, wobf, 131072);
    cvt_kernel<<<2048, 256, 0, stream>>>(w1 + (size_t)l * 4194304, w1bf, 524288);
    gemm_kernel<64, 2, 0><<<512, 256, 0, stream>>>(
        vbf, 1024, wobf, 1024, bo + l * 1024, cfA, cfB, nullptr, 1024, 512);
    ln_kernel<<<2048, 256, 0, stream>>>(cfA, cfB, hf, ln1g + l * 1024, ln1b + l * 1024,
                                        x1f, x1bf);
    gemm_kernel<128, 1, 1><<<512, 256, 0, stream>>>(
        x1bf, 1024, w1bf, 1024, b1 + l * 4096, nullptr, nullptr, ffbf, 4096, 1024);
    cvt_kernel<<<2048, 256, 0, stream>>>(w2 + (size_t)l * 4194304, w2bf, 524288);
    gemm_kernel<64, 2, 0><<<512, 256, 0, stream>>>(
        ffbf, 4096, w2bf, 4096, b2 + l * 1024, cfA, cfB, nullptr, 1024, 2048);
    ln_kernel<<<2048, 256, 0, stream>>>(cfA, cfB, x1f, ln2g + l * 1024, ln2b + l * 1024,
                                        hf, hbf);
  }
  cvt_kernel<<<2048, 256, 0, stream>>>(outw, outwbf, 4096000);
  gemm256_kernel<<<1000, 512, 131072, stream>>>(hbf, 1024, outwbf, 1024, outb, out, 32000, 1024);
}

// Round 7
// 1052.001 us; speedup vs baseline: 1.0864x; 1.0043x over previous
//
#include <hip/hip_runtime.h>
#include <math.h>

typedef float f32x4 __attribute__((ext_vector_type(4)));
typedef unsigned short u16x8 __attribute__((ext_vector_type(8)));
typedef unsigned short u16x4 __attribute__((ext_vector_type(4)));
typedef __bf16 bf16x8 __attribute__((ext_vector_type(8)));
typedef unsigned int u32;

#define DEV static __device__ __forceinline__

DEV unsigned short f2bf(float f) {            // RNE f32 -> bf16 bits
  unsigned u = __float_as_uint(f);
  u += 0x7FFFu + ((u >> 16) & 1u);
  return (unsigned short)(u >> 16);
}
DEV float bf2f(unsigned short s) { return __uint_as_float(((unsigned)s) << 16); }
DEV bf16x8 asbf(u16x8 v) { return __builtin_bit_cast(bf16x8, v); }

DEV void gload16(const void* g, void* l) {    // async global->LDS, 16B/lane, wave-uniform LDS base
  __builtin_amdgcn_global_load_lds((const __attribute__((address_space(1))) u32*)g,
                                   (__attribute__((address_space(3))) u32*)l, 16, 0, 0);
}

// ---------------------------------------------------------------- f32 -> bf16 bulk convert
__global__ void cvt_kernel(const float* __restrict__ in, unsigned short* __restrict__ out, int n8) {
  for (int i = blockIdx.x * 256 + threadIdx.x; i < n8; i += gridDim.x * 256) {
    const float* s = in + (size_t)i * 8;
    f32x4 a = *(const f32x4*)s, b = *(const f32x4*)(s + 4);
    u16x8 o;
    for (int j = 0; j < 4; ++j) { o[j] = f2bf(a[j]); o[j + 4] = f2bf(b[j]); }
    *(u16x8*)(out + (size_t)i * 8) = o;
  }
}

// ---------------------------------------------------------------- embed
__global__ void embed_kernel(const int* __restrict__ x, const float* __restrict__ tok,
                             const float* __restrict__ pos, float* __restrict__ h,
                             unsigned short* __restrict__ hbf) {
  int t = blockIdx.x, tid = threadIdx.x;
  int v = x[t], s = t & 1023;                 // S = 1024
  f32x4 a = *(const f32x4*)(tok + (size_t)v * 1024 + tid * 4);
  f32x4 b = *(const f32x4*)(pos + (size_t)s * 1024 + tid * 4);
  f32x4 r = a + b;
  *(f32x4*)(h + (size_t)t * 1024 + tid * 4) = r;
  u16x4 rb;
  for (int i = 0; i < 4; ++i) rb[i] = f2bf(r[i]);
  *(u16x4*)(hbf + (size_t)t * 1024 + tid * 4) = rb;
}

// ---------------------------------------------------------------- LayerNorm(preA + preB + res)
__global__ __launch_bounds__(256) void ln_kernel(const float* __restrict__ preA,
    const float* __restrict__ preB, const float* __restrict__ res,
    const float* __restrict__ g, const float* __restrict__ bta,
    float* __restrict__ outf, unsigned short* __restrict__ outbf) {
  int row = blockIdx.x, tid = threadIdx.x;
  size_t base = (size_t)row * 1024 + tid * 4;
  f32x4 xv = *(const f32x4*)(preA + base);
  xv += *(const f32x4*)(preB + base);
  xv += *(const f32x4*)(res + base);
  float s = xv[0] + xv[1] + xv[2] + xv[3];
  float s2 = xv[0]*xv[0] + xv[1]*xv[1] + xv[2]*xv[2] + xv[3]*xv[3];
  for (int m = 1; m < 64; m <<= 1) { s += __shfl_xor(s, m); s2 += __shfl_xor(s2, m); }
  __shared__ float red[8];
  int w = tid >> 6;
  if ((tid & 63) == 0) { red[w * 2] = s; red[w * 2 + 1] = s2; }
  __syncthreads();
  s = red[0] + red[2] + red[4] + red[6];
  s2 = red[1] + red[3] + red[5] + red[7];
  float mu = s * (1.f / 1024.f);
  float var = s2 * (1.f / 1024.f) - mu * mu;
  float rs = rsqrtf(var + 1e-5f);
  f32x4 gv = *(const f32x4*)(g + tid * 4);
  f32x4 bv = *(const f32x4*)(bta + tid * 4);
  f32x4 o; u16x4 ob;
  for (int i = 0; i < 4; ++i) { o[i] = (xv[i] - mu) * rs * gv[i] + bv[i]; ob[i] = f2bf(o[i]); }
  *(f32x4*)(outf + base) = o;
  *(u16x4*)(outbf + base) = ob;
}

// ---------------------------------------------------------------- QKV (shared 64x64 weight per head)
__global__ __launch_bounds__(256) void qkv_kernel(const unsigned short* __restrict__ hbf,
    const float* __restrict__ wq, const float* __restrict__ wk, const float* __restrict__ wv,
    unsigned short* __restrict__ q, unsigned short* __restrict__ k, unsigned short* __restrict__ v) {
  __shared__ float Wt[3][64 * 65];            // transposed [d][e], pad 65: conflict-free
  int tid = threadIdx.x;
  for (int j = 0; j < 16; ++j) {
    int idx = tid + 256 * j; int e = idx >> 6, d = idx & 63;
    Wt[0][d * 65 + e] = wq[idx];
    Wt[1][d * 65 + e] = wk[idx];
    Wt[2][d * 65 + e] = wv[idx];
  }
  __syncthreads();
  int lane = tid & 63, w = tid >> 6;
  for (int it = 0; it < 8; ++it) {
    int th = blockIdx.x * 32 + w * 8 + it;    // token-head in [0, 32768)
    int t = th >> 4, hh = th & 15;
    size_t off = (size_t)t * 1024 + hh * 64;
    float xv = bf2f(hbf[off + lane]);
    float aq = 0.f, ak = 0.f, av = 0.f;
    for (int d = 0; d < 64; ++d) {
      float xd = __shfl(xv, d);
      aq = fmaf(Wt[0][d * 65 + lane], xd, aq);
      ak = fmaf(Wt[1][d * 65 + lane], xd, ak);
      av = fmaf(Wt[2][d * 65 + lane], xd, av);
    }
    q[off + lane] = f2bf(aq);
    k[off + lane] = f2bf(ak);
    v[off + lane] = f2bf(av);
  }
}

// ---------------------------------------------------------------- V transpose: [b,s,h,e] -> [b,h,e,s]
__global__ __launch_bounds__(256) void vtrans_kernel(const unsigned short* __restrict__ v,
                                                     unsigned short* __restrict__ vt) {
  __shared__ unsigned short T[64 * 72];
  int tid = threadIdx.x, st = blockIdx.x, bh = blockIdx.y;
  int b = bh >> 4, hh = bh & 15;
  for (int j = 0; j < 2; ++j) {
    int idx = tid + 256 * j; int s = idx >> 3, e0 = (idx & 7) * 8;
    u16x8 r = *(const u16x8*)(v + ((size_t)(b * 1024 + st * 64 + s) * 16 + hh) * 64 + e0);
    for (int i = 0; i < 8; ++i) T[(e0 + i) * 72 + s] = r[i];
  }
  __syncthreads();
  for (int j = 0; j < 2; ++j) {
    int idx = tid + 256 * j; int e = idx >> 3, s0 = (idx & 7) * 8;
    u16x8 r = *(const u16x8*)(&T[e * 72 + s0]);
    *(u16x8*)(vt + ((size_t)(b * 16 + hh) * 64 + e) * 1024 + st * 64 + s0) = r;
  }
}

// ---------------------------------------------------------------- flash attention, KVBLK=128
__global__ __launch_bounds__(256, 2) void attn_kernel(const unsigned short* __restrict__ qb,
    const unsigned short* __restrict__ kb, const unsigned short* __restrict__ vtb,
    unsigned short* __restrict__ ob) {
  constexpr int PK = 72, PV = 136, PP = 136;
  __shared__ unsigned short Ks[128 * PK], Vs[64 * PV], Ps[4][16 * PP];
  int tid = threadIdx.x, lane = tid & 63, w = tid >> 6;
  int l15 = lane & 15, lg = lane >> 4;
  int qt = blockIdx.x, bh = blockIdx.y, b = bh >> 4, hh = bh & 15;
  int q0 = qt * 64 + w * 16;
  const unsigned short* qrow = qb + ((size_t)(b * 1024 + q0 + l15) * 16 + hh) * 64 + lg * 8;
  bf16x8 qa0 = asbf(*(const u16x8*)qrow);
  bf16x8 qa1 = asbf(*(const u16x8*)(qrow + 32));
  float m_[4] = {-1e30f, -1e30f, -1e30f, -1e30f};
  float ls[4] = {0.f, 0.f, 0.f, 0.f};
  f32x4 oacc[4] = {};
  const float inv = 1.f / 32.f;
  for (int kt = 0; kt < 8; ++kt) {
    for (int j = 0; j < 4; ++j) {
      int idx = tid + 256 * j;                // 1024 vec-slots
      int r = idx >> 3, c0 = (idx & 7) * 8;   // K: 128 rows x 8 col-blocks
      *(u16x8*)(&Ks[r * PK + c0]) =
          *(const u16x8*)(kb + ((size_t)(b * 1024 + kt * 128 + r) * 16 + hh) * 64 + c0);
      int rv = idx >> 4, cv = (idx & 15) * 8; // V^T: 64 e-rows x 16 s-blocks
      *(u16x8*)(&Vs[rv * PV + cv]) =
          *(const u16x8*)(vtb + ((size_t)((b * 16 + hh) * 64) + rv) * 1024 + kt * 128 + cv);
    }
    __syncthreads();
    f32x4 sf[8] = {};
#pragma unroll
    for (int n = 0; n < 8; ++n) {
      bf16x8 k0 = asbf(*(const u16x8*)(&Ks[(n * 16 + l15) * PK + lg * 8]));
      bf16x8 k1 = asbf(*(const u16x8*)(&Ks[(n * 16 + l15) * PK + 32 + lg * 8]));
      sf[n] = __builtin_amdgcn_mfma_f32_16x16x32_bf16(qa0, k0, sf[n], 0, 0, 0);
      sf[n] = __builtin_amdgcn_mfma_f32_16x16x32_bf16(qa1, k1, sf[n], 0, 0, 0);
    }
#pragma unroll
    for (int n = 0; n < 8; ++n) sf[n] *= inv;
    float mx[4], sc[4];
#pragma unroll
    for (int r = 0; r < 4; ++r) {
      float t0 = fmaxf(fmaxf(fmaxf(sf[0][r], sf[1][r]), fmaxf(sf[2][r], sf[3][r])),
                       fmaxf(fmaxf(sf[4][r], sf[5][r]), fmaxf(sf[6][r], sf[7][r])));
      for (int msk = 1; msk < 16; msk <<= 1) t0 = fmaxf(t0, __shfl_xor(t0, msk));
      mx[r] = fmaxf(m_[r], t0);
      sc[r] = __expf(m_[r] - mx[r]);
      m_[r] = mx[r];
    }
    float rsum[4] = {0.f, 0.f, 0.f, 0.f};
    unsigned short pb[8][4];
#pragma unroll
    for (int n = 0; n < 8; ++n)
#pragma unroll
      for (int r = 0; r < 4; ++r) {
        float pv = __expf(sf[n][r] - mx[r]);
        rsum[r] += pv;
        pb[n][r] = f2bf(pv);
      }
#pragma unroll
    for (int r = 0; r < 4; ++r) {
      float t0 = rsum[r];
      for (int msk = 1; msk < 16; msk <<= 1) t0 += __shfl_xor(t0, msk);
      ls[r] = ls[r] * sc[r] + t0;
    }
#pragma unroll
    for (int n = 0; n < 4; ++n)
#pragma unroll
      for (int r = 0; r < 4; ++r) oacc[n][r] *= sc[r];
    unsigned short* pw = Ps[w];                // per-wave region: no block barrier needed
#pragma unroll
    for (int n = 0; n < 8; ++n)
#pragma unroll
      for (int r = 0; r < 4; ++r)
        pw[(4 * lg + r) * PP + n * 16 + l15] = pb[n][r];
    asm volatile("s_waitcnt lgkmcnt(0)" ::: "memory");
    __builtin_amdgcn_sched_barrier(0);
    bf16x8 pa[4];
#pragma unroll
    for (int ks = 0; ks < 4; ++ks)
      pa[ks] = asbf(*(const u16x8*)(&pw[l15 * PP + ks * 32 + lg * 8]));
#pragma unroll
    for (int n = 0; n < 4; ++n) {
#pragma unroll
      for (int ks = 0; ks < 4; ++ks) {
        bf16x8 v0 = asbf(*(const u16x8*)(&Vs[(n * 16 + l15) * PV + ks * 32 + lg * 8]));
        oacc[n] = __builtin_amdgcn_mfma_f32_16x16x32_bf16(pa[ks], v0, oacc[n], 0, 0, 0);
      }
    }
    __syncthreads();
  }
#pragma unroll
  for (int n = 0; n < 4; ++n)
#pragma unroll
    for (int r = 0; r < 4; ++r) {
      float o = oacc[n][r] / ls[r];
      ob[((size_t)(b * 1024 + q0 + 4 * lg + r) * 16 + hh) * 64 + n * 16 + l15] = f2bf(o);
    }
}

// ---------------------------------------------------------------- bf16 GEMM, m97 structure (layer GEMMs)
template <int BM, int KSPLIT, int EPI>
__global__ __launch_bounds__(256) void gemm_kernel(
    const unsigned short* __restrict__ A, int lda,
    const unsigned short* __restrict__ B, int ldb,
    const float* __restrict__ bias,
    float* __restrict__ CfA, float* __restrict__ CfB, unsigned short* __restrict__ Cb,
    int ldc, int Ksub) {
  constexpr int LOGMT = (BM == 128) ? 4 : 5;  // M = 2048 always
  constexpr int MT = 2048 / BM;
  constexpr int MI = BM / 32;                 // A-frags per wave
  __shared__ alignas(16) char smem[33280];    // max(stage 32KB, Cs 64*130*4)
  unsigned short* As = (unsigned short*)smem;           // [2][BM*32]
  unsigned short* Bs = As + 2 * BM * 32;                // [2][128*32]
  float* Cs = (float*)smem;                             // epilogue bounce, stride 130

  int wg = blockIdx.x;
  int mt = wg & (MT - 1);
  int rest = wg >> LOGMT;
  int nt, kh;
  if (KSPLIT == 2) { nt = rest & 7; kh = rest >> 3; }   // NT must be 8 when split
  else { nt = rest; kh = 0; }
  int m0 = mt * BM, n0 = nt * 128;
  const unsigned short* Ae = A + (KSPLIT == 2 ? (size_t)kh * Ksub : 0);
  const unsigned short* Be = B + (KSPLIT == 2 ? (size_t)kh * Ksub : 0);

  int tid = threadIdx.x, ln = tid & 63, wv = tid >> 6;
  int l15 = ln & 15, lg = ln >> 4;
  int wm = (wv >> 1) * (BM / 2), wn = (wv & 1) * 64;

  auto stage = [&](int buf, int k0) {
    for (int j = 0; j < BM / 64; ++j) {
      int row = j * 64 + wv * 16 + (ln >> 2);
      gload16(Ae + (size_t)(m0 + row) * lda + k0 + (ln & 3) * 8,
              &As[buf * (BM * 32) + (j * 64 + wv * 16) * 32]);
    }
    for (int j = 0; j < 2; ++j) {
      int row = j * 64 + wv * 16 + (ln >> 2);
      gload16(Be + (size_t)(n0 + row) * ldb + k0 + (ln & 3) * 8,
              &Bs[buf * 4096 + (j * 64 + wv * 16) * 32]);
    }
  };

  f32x4 acc[MI][4] = {};
  auto compute = [&](int buf) {
    const unsigned short* as = &As[buf * (BM * 32)];
    const unsigned short* bs = &Bs[buf * 4096];
    bf16x8 af[MI], bfn[4];
    for (int mi = 0; mi < MI; ++mi)
      af[mi] = asbf(*(const u16x8*)&as[(wm + mi * 16 + l15) * 32 + lg * 8]);
    for (int ni = 0; ni < 4; ++ni)
      bfn[ni] = asbf(*(const u16x8*)&bs[(wn + ni * 16 + l15) * 32 + lg * 8]);
    for (int mi = 0; mi < MI; ++mi)
      for (int ni = 0; ni < 4; ++ni)
        acc[mi][ni] = __builtin_amdgcn_mfma_f32_16x16x32_bf16(af[mi], bfn[ni], acc[mi][ni], 0, 0, 0);
  };

  stage(0, 0);
  __syncthreads();
  int ntk = Ksub >> 5, cur = 0;
  for (int t = 0; t < ntk - 1; ++t) {
    stage(cur ^ 1, (t + 1) << 5);
    compute(cur);
    __syncthreads();
    cur ^= 1;
  }
  compute(cur);

  float* Cf = (kh == 0) ? CfA : CfB;
  const bool addb = (kh == 0);
  for (int p = 0; p < BM / 64; ++p) {
    __syncthreads();
    if ((wm >> 6) == p) {
      int rb = wm & 63;
      for (int mi = 0; mi < MI; ++mi)
        for (int ni = 0; ni < 4; ++ni) {
          int cn = wn + ni * 16 + l15;
          float bv = addb ? bias[n0 + cn] : 0.f;
          for (int r = 0; r < 4; ++r) {
            float vv = acc[mi][ni][r] + bv;
            if (EPI == 1) vv = 0.5f * vv * (1.f + erff(vv * 0.70710678118f));
            Cs[(rb + mi * 16 + 4 * lg + r) * 130 + cn] = vv;
          }
        }
    }
    __syncthreads();
    int row = tid >> 3;
    for (int ri = 0; ri < 2; ++ri) {
      int lr = ri * 32 + row;
      size_t gbase = (size_t)(m0 + p * 64 + lr) * ldc + n0;
      if (EPI == 0) {
        int c4 = (tid & 7) * 4;
        for (int j = 0; j < 4; ++j)
          *(f32x4*)(Cf + gbase + c4 + j * 32) = *(const f32x4*)&Cs[lr * 130 + c4 + j * 32];
      } else {
        for (int j = 0; j < 2; ++j) {
          int cc = (tid & 7) * 8 + j * 64;
          f32x4 v0 = *(const f32x4*)&Cs[lr * 130 + cc];
          f32x4 v1 = *(const f32x4*)&Cs[lr * 130 + cc + 4];
          u16x8 o;
          for (int i = 0; i < 4; ++i) { o[i] = f2bf(v0[i]); o[i + 4] = f2bf(v1[i]); }
          *(u16x8*)(Cb + gbase + cc) = o;
        }
      }
    }
  }
}

// ---------------------------------------------------------------- 256x256 BK=64 4-phase GEMM (logits)
// Counted-vmcnt schedule (T4): deadline-ordered half-tile staging, waits 6/6/-/4, never 0 mid-loop.
// B rows permuted in LDS: p = (ni>>1)*128 + wn*32 + (ni&1)*16 + r%32-ish so ni01/ni23 = gload pairs.
__global__ __launch_bounds__(512, 1) void gemm256_kernel(
    const unsigned short* __restrict__ A, int lda,
    const unsigned short* __restrict__ B, int ldb,
    const float* __restrict__ bias, float* __restrict__ C, int ldc, int K) {
  extern __shared__ unsigned short sm[];      // 65536 elems = 128 KiB
  int b = blockIdx.x;
  int c = (int)gridDim.x >> 3;
  int wg = (b & 7) * c + (b >> 3);            // XCD-contiguous (grid % 8 == 0)
  int mt = wg & 7, nt = wg >> 3;
  int m0 = mt * 256, n0 = nt * 256;

  int tid = threadIdx.x, ln = tid & 63, wv = tid >> 6;
  int l15 = ln & 15, lg = ln >> 4;
  int wm = wv >> 2, wn = wv & 3;              // 2M x 4N waves; wave tile 128x64
  int l7 = l15 & 7;

  // staging: dest LDS row (within chunk g) = tid>>3, dest 16B-blk = tid&7,
  // source col-blk pre-inverse-swizzled with key (tid>>3)&7
  int srow = tid >> 3, sblk = (tid & 7) ^ (srow & 7);
  const unsigned short* Ab = A + (size_t)(m0 + srow) * lda + sblk * 8;
  // B global row for LDS row p = g*64+srow (row-permuted layout):
  const unsigned short* BbG[4];
#pragma unroll
  for (int g = 0; g < 4; ++g) {
    int p = g * 64 + srow;
    int j = p & 127;
    int r = ((j >> 5) << 6) + ((p >> 7) << 5) + (j & 31);
    BbG[g] = B + (size_t)(n0 + r) * ldb + sblk * 8;
  }
  auto stA = [&](int e, int g, int k0) {
    gload16(Ab + ((size_t)g * 64) * lda + k0, &sm[e * 16384 + g * 4096 + wv * 512]);
  };
  auto stB = [&](int e, int g, int k0) {
    gload16(BbG[g] + k0, &sm[32768 + e * 16384 + g * 4096 + wv * 512]);
  };

  auto ldsA = [&](int d, int mi, int ks) -> bf16x8 {
    int row = wm * 128 + mi * 16 + l15;
    return asbf(*(const u16x8*)&sm[d * 16384 + row * 64 + (((ks << 2) | lg) ^ l7) * 8]);
  };
  auto ldsB = [&](int d, int ni, int ks) -> bf16x8 {
    int p = ((ni >> 1) << 7) + wn * 32 + ((ni & 1) << 4) + l15;   // permuted row
    return asbf(*(const u16x8*)&sm[32768 + d * 16384 + p * 64 + (((ks << 2) | lg) ^ l7) * 8]);
  };

  f32x4 acc[8][4] = {};
  bf16x8 Af[4][2], Bf01[2][2], Bf23[2][2];

#define PH_OPEN() __builtin_amdgcn_s_barrier(); \
  asm volatile("s_waitcnt lgkmcnt(0)" ::: "memory"); \
  __builtin_amdgcn_sched_barrier(0); __builtin_amdgcn_s_setprio(1)

  // prologue: tile 0 -> buf 0, full drain (one-time)
  stA(0, 0, 0); stA(0, 2, 0); stB(0, 0, 0); stB(0, 1, 0);
  stB(0, 2, 0); stB(0, 3, 0); stA(0, 1, 0); stA(0, 3, 0);
  asm volatile("s_waitcnt vmcnt(0)" ::: "memory");
  __builtin_amdgcn_s_barrier();

  int ntk = K >> 6;
  for (int kk = 0; kk < ntk; ++kk) {
    int d = kk & 1, e = d ^ 1, k1 = (kk + 1) << 6;
    bool pf = (kk + 1 < ntk);
    { // P1: reads B01(d) + A mi0-3(d); stage A(e)g0,g2 + B(e)g0,g1  [deadline P1(kk+1)]
#pragma unroll
      for (int ni = 0; ni < 2; ++ni) { Bf01[ni][0] = ldsB(d, ni, 0); Bf01[ni][1] = ldsB(d, ni, 1); }
#pragma unroll
      for (int mi = 0; mi < 4; ++mi) { Af[mi][0] = ldsA(d, mi, 0); Af[mi][1] = ldsA(d, mi, 1); }
      if (pf) { stA(e, 0, k1); stA(e, 2, k1); stB(e, 0, k1); stB(e, 1, k1); }
      PH_OPEN();
#pragma unroll
      for (int mi = 0; mi < 4; ++mi)
#pragma unroll
        for (int ni = 0; ni < 2; ++ni) {
          acc[mi][ni] = __builtin_amdgcn_mfma_f32_16x16x32_bf16(Af[mi][0], Bf01[ni][0], acc[mi][ni], 0, 0, 0);
          acc[mi][ni] = __builtin_amdgcn_mfma_f32_16x16x32_bf16(Af[mi][1], Bf01[ni][1], acc[mi][ni], 0, 0, 0);
        }
      __builtin_amdgcn_s_setprio(0);
      if (pf) { asm volatile("s_waitcnt vmcnt(6)" ::: "memory"); }
      else    { asm volatile("s_waitcnt vmcnt(2)" ::: "memory"); }
      __builtin_amdgcn_s_barrier();
    }
    { // P2: reads B23(d); stage B(e)g2,g3  [deadline P2(kk+1)]
#pragma unroll
      for (int ni = 0; ni < 2; ++ni) { Bf23[ni][0] = ldsB(d, 2 + ni, 0); Bf23[ni][1] = ldsB(d, 2 + ni, 1); }
      if (pf) { stB(e, 2, k1); stB(e, 3, k1); }
      PH_OPEN();
#pragma unroll
      for (int mi = 0; mi < 4; ++mi)
#pragma unroll
        for (int ni = 0; ni < 2; ++ni) {
          acc[mi][2 + ni] = __builtin_amdgcn_mfma_f32_16x16x32_bf16(Af[mi][0], Bf23[ni][0], acc[mi][2 + ni], 0, 0, 0);
          acc[mi][2 + ni] = __builtin_amdgcn_mfma_f32_16x16x32_bf16(Af[mi][1], Bf23[ni][1], acc[mi][2 + ni], 0, 0, 0);
        }
      __builtin_amdgcn_s_setprio(0);
      if (pf) { asm volatile("s_waitcnt vmcnt(6)" ::: "memory"); }
      else    { asm volatile("s_waitcnt vmcnt(0)" ::: "memory"); }
      __builtin_amdgcn_s_barrier();
    }
    { // P3: reads A mi4-7(d); stage A(e)g1,g3  [deadline P3(kk+1)]
#pragma unroll
      for (int mi = 0; mi < 4; ++mi) { Af[mi][0] = ldsA(d, 4 + mi, 0); Af[mi][1] = ldsA(d, 4 + mi, 1); }
      if (pf) { stA(e, 1, k1); stA(e, 3, k1); }
      PH_OPEN();
#pragma unroll
      for (int mi = 0; mi < 4; ++mi)
#pragma unroll
        for (int ni = 0; ni < 2; ++ni) {
          acc[4 + mi][2 + ni] = __builtin_amdgcn_mfma_f32_16x16x32_bf16(Af[mi][0], Bf23[ni][0], acc[4 + mi][2 + ni], 0, 0, 0);
          acc[4 + mi][2 + ni] = __builtin_amdgcn_mfma_f32_16x16x32_bf16(Af[mi][1], Bf23[ni][1], acc[4 + mi][2 + ni], 0, 0, 0);
        }
      __builtin_amdgcn_s_setprio(0);
      __builtin_amdgcn_s_barrier();           // no vmcnt: P4-pre has no LDS reads
    }
    { // P4: no reads; MFMA reuses Af(4-7) x B01
      PH_OPEN();
#pragma unroll
      for (int mi = 0; mi < 4; ++mi)
#pragma unroll
        for (int ni = 0; ni < 2; ++ni) {
          acc[4 + mi][ni] = __builtin_amdgcn_mfma_f32_16x16x32_bf16(Af[mi][0], Bf01[ni][0], acc[4 + mi][ni], 0, 0, 0);
          acc[4 + mi][ni] = __builtin_amdgcn_mfma_f32_16x16x32_bf16(Af[mi][1], Bf01[ni][1], acc[4 + mi][ni], 0, 0, 0);
        }
      __builtin_amdgcn_s_setprio(0);
      if (pf) { asm volatile("s_waitcnt vmcnt(4)" ::: "memory"); }
      __builtin_amdgcn_s_barrier();
    }
  }
#undef PH_OPEN

  // ---- epilogue: LDS bounce (per-wave 64x64 f32 region), full-line f32x4 stores
  float* fb = (float*)sm;
  int fbase = wv * 4096;                      // 8 waves x 16 KiB = 128 KiB exactly
  float bv[4];
#pragma unroll
  for (int ni = 0; ni < 4; ++ni) bv[ni] = bias[n0 + wn * 64 + ni * 16 + l15];
#pragma unroll
  for (int p = 0; p < 2; ++p) {
    if (p) { asm volatile("s_waitcnt lgkmcnt(0)" ::: "memory"); __builtin_amdgcn_sched_barrier(0); }
#pragma unroll
    for (int mi = 0; mi < 4; ++mi)
#pragma unroll
      for (int ni = 0; ni < 4; ++ni)
#pragma unroll
        for (int r = 0; r < 4; ++r)
          fb[fbase + (mi * 16 + lg * 4 + r) * 64 + ni * 16 + l15] = acc[4 * p + mi][ni][r] + bv[ni];
    asm volatile("s_waitcnt lgkmcnt(0)" ::: "memory");
    __builtin_amdgcn_sched_barrier(0);
#pragma unroll
    for (int i = 0; i < 16; ++i) {
      int row = i * 4 + lg;
      f32x4 v = *(const f32x4*)&fb[fbase + row * 64 + l15 * 4];
      int grow = m0 + wm * 128 + p * 64 + row;
      *(f32x4*)(&C[(size_t)grow * ldc + n0 + wn * 64 + l15 * 4]) = v;
    }
  }
}

// ----------------------------------------------------------------
extern "C" void kernel_launch(void* const* d_in, const int* in_sizes, int n_in,
                              void* d_out, int out_size, void* d_ws, size_t ws_size,
                              hipStream_t stream) {
  const int* x = (const int*)d_in[0];
  const float* tok = (const float*)d_in[1];
  const float* pos = (const float*)d_in[2];
  const float* wq = (const float*)d_in[3];
  const float* wk = (const float*)d_in[4];
  const float* wv = (const float*)d_in[5];
  const float* wo = (const float*)d_in[6];
  const float* bo = (const float*)d_in[7];
  const float* ln1g = (const float*)d_in[8];
  const float* ln1b = (const float*)d_in[9];
  const float* ln2g = (const float*)d_in[10];
  const float* ln2b = (const float*)d_in[11];
  const float* w1 = (const float*)d_in[12];
  const float* b1 = (const float*)d_in[13];
  const float* w2 = (const float*)d_in[14];
  const float* b2 = (const float*)d_in[15];
  const float* outw = (const float*)d_in[16];
  const float* outb = (const float*)d_in[17];
  float* out = (float*)d_out;

  const size_t MiB = 1 << 20;
  const size_t need = 4 * MiB + 65536000;
  if (ws_size < need) return;
  char* base = (char*)d_ws;
  unsigned short* hbf = (unsigned short*)base;            // 4 MiB, persistent
  char* R = base + 4 * MiB;
  float* hf  = (float*)(R);                               // 8 MiB
  float* x1f = (float*)(R + 8 * MiB);                     // 8 MiB
  unsigned short* x1bf = (unsigned short*)(R + 16 * MiB); // 4 MiB
  float* cfA = (float*)(R + 20 * MiB);                    // 8 MiB
  float* cfB = (float*)(R + 28 * MiB);                    // 8 MiB
  unsigned short* qs = (unsigned short*)(R + 36 * MiB);   // 6 slots x 4 MiB
  const size_t SL = 2048ull * 1024;
  unsigned short* qbf = qs;
  unsigned short* kbf = qs + SL;
  unsigned short* vbf = qs + 2 * SL;                      // also attn-out
  unsigned short* vtbf = qs + 3 * SL;                     // also wobf
  unsigned short* wobf = vtbf;
  unsigned short* w1bf = qbf;
  unsigned short* w2bf = qbf;
  unsigned short* ffbf = vbf;
  unsigned short* outwbf = (unsigned short*)R;            // 62.5 MiB, after layers

  embed_kernel<<<2048, 256, 0, stream>>>(x, tok, pos, hf, hbf);
  for (int l = 0; l < 4; ++l) {
    qkv_kernel<<<1024, 256, 0, stream>>>(hbf, wq + l * 4096, wk + l * 4096, wv + l * 4096,
                                         qbf, kbf, vbf);
    vtrans_kernel<<<dim3(16, 32), 256, 0, stream>>>(vbf, vtbf);
    attn_kernel<<<dim3(16, 32), 256, 0, stream>>>(qbf, kbf, vtbf, vbf);
    cvt_kernel<<<512, 256, 0, stream>>>(wo + (size_t)l * 1048576, wobf, 131072);
    cvt_kernel<<<2048, 256, 0, stream>>>(w1 + (size_t)l * 4194304, w1bf, 524288);
    gemm_kernel<64, 2, 0><<<512, 256, 0, stream>>>(
        vbf, 1024, wobf, 1024, bo + l * 1024, cfA, cfB, nullptr, 1024, 512);
    ln_kernel<<<2048, 256, 0, stream>>>(cfA, cfB, hf, ln1g + l * 1024, ln1b + l * 1024,
                                        x1f, x1bf);
    gemm_kernel<128, 1, 1><<<512, 256, 0, stream>>>(
        x1bf, 1024, w1bf, 1024, b1 + l * 4096, nullptr, nullptr, ffbf, 4096, 1024);
    cvt_kernel<<<2048, 256, 0, stream>>>(w2 + (size_t)l * 4194304, w2bf, 524288);
    gemm_kernel<64, 2, 0><<<512, 256, 0, stream>>>(
        ffbf, 4096, w2bf, 4096, b2 + l * 1024, cfA, cfB, nullptr, 1024, 2048);
    ln_kernel<<<2048, 256, 0, stream>>>(cfA, cfB, x1f, ln2g + l * 1024, ln2b + l * 1024,
                                        hf, hbf);
  }
  cvt_kernel<<<2048, 256, 0, stream>>>(outw, outwbf, 4096000);
  gemm256_kernel<<<1000, 512, 131072, stream>>>(hbf, 1024, outwbf, 1024, outb, out, 32000, 1024);
}

// Round 8
// 891.549 us; speedup vs baseline: 1.2819x; 1.1800x over previous
//
#include <hip/hip_runtime.h>
#include <math.h>

typedef float f32x4 __attribute__((ext_vector_type(4)));
typedef unsigned short u16x8 __attribute__((ext_vector_type(8)));
typedef unsigned short u16x4 __attribute__((ext_vector_type(4)));
typedef __bf16 bf16x8 __attribute__((ext_vector_type(8)));
typedef unsigned int u32;

#define DEV static __device__ __forceinline__

DEV unsigned short f2bf(float f) {            // RNE f32 -> bf16 bits
  unsigned u = __float_as_uint(f);
  u += 0x7FFFu + ((u >> 16) & 1u);
  return (unsigned short)(u >> 16);
}
DEV float bf2f(unsigned short s) { return __uint_as_float(((unsigned)s) << 16); }
DEV bf16x8 asbf(u16x8 v) { return __builtin_bit_cast(bf16x8, v); }

DEV void gload16(const void* g, void* l) {    // async global->LDS, 16B/lane, wave-uniform LDS base
  __builtin_amdgcn_global_load_lds((const __attribute__((address_space(1))) u32*)g,
                                   (__attribute__((address_space(3))) u32*)l, 16, 0, 0);
}

// ---------------------------------------------------------------- f32 -> bf16 bulk convert
__global__ void cvt_kernel(const float* __restrict__ in, unsigned short* __restrict__ out, int n8) {
  for (int i = blockIdx.x * 256 + threadIdx.x; i < n8; i += gridDim.x * 256) {
    const float* s = in + (size_t)i * 8;
    f32x4 a = *(const f32x4*)s, b = *(const f32x4*)(s + 4);
    u16x8 o;
    for (int j = 0; j < 4; ++j) { o[j] = f2bf(a[j]); o[j + 4] = f2bf(b[j]); }
    *(u16x8*)(out + (size_t)i * 8) = o;
  }
}

// ---------------------------------------------------------------- embed
__global__ void embed_kernel(const int* __restrict__ x, const float* __restrict__ tok,
                             const float* __restrict__ pos, float* __restrict__ h,
                             unsigned short* __restrict__ hbf) {
  int t = blockIdx.x, tid = threadIdx.x;
  int v = x[t], s = t & 1023;                 // S = 1024
  f32x4 a = *(const f32x4*)(tok + (size_t)v * 1024 + tid * 4);
  f32x4 b = *(const f32x4*)(pos + (size_t)s * 1024 + tid * 4);
  f32x4 r = a + b;
  *(f32x4*)(h + (size_t)t * 1024 + tid * 4) = r;
  u16x4 rb;
  for (int i = 0; i < 4; ++i) rb[i] = f2bf(r[i]);
  *(u16x4*)(hbf + (size_t)t * 1024 + tid * 4) = rb;
}

// ---------------------------------------------------------------- LayerNorm(preA + preB + res)
__global__ __launch_bounds__(256) void ln_kernel(const float* __restrict__ preA,
    const float* __restrict__ preB, const float* __restrict__ res,
    const float* __restrict__ g, const float* __restrict__ bta,
    float* __restrict__ outf, unsigned short* __restrict__ outbf) {
  int row = blockIdx.x, tid = threadIdx.x;
  size_t base = (size_t)row * 1024 + tid * 4;
  f32x4 xv = *(const f32x4*)(preA + base);
  xv += *(const f32x4*)(preB + base);
  xv += *(const f32x4*)(res + base);
  float s = xv[0] + xv[1] + xv[2] + xv[3];
  float s2 = xv[0]*xv[0] + xv[1]*xv[1] + xv[2]*xv[2] + xv[3]*xv[3];
  for (int m = 1; m < 64; m <<= 1) { s += __shfl_xor(s, m); s2 += __shfl_xor(s2, m); }
  __shared__ float red[8];
  int w = tid >> 6;
  if ((tid & 63) == 0) { red[w * 2] = s; red[w * 2 + 1] = s2; }
  __syncthreads();
  s = red[0] + red[2] + red[4] + red[6];
  s2 = red[1] + red[3] + red[5] + red[7];
  float mu = s * (1.f / 1024.f);
  float var = s2 * (1.f / 1024.f) - mu * mu;
  float rs = rsqrtf(var + 1e-5f);
  f32x4 gv = *(const f32x4*)(g + tid * 4);
  f32x4 bv = *(const f32x4*)(bta + tid * 4);
  f32x4 o; u16x4 ob;
  for (int i = 0; i < 4; ++i) { o[i] = (xv[i] - mu) * rs * gv[i] + bv[i]; ob[i] = f2bf(o[i]); }
  *(f32x4*)(outf + base) = o;
  *(u16x4*)(outbf + base) = ob;
}

// ---------------------------------------------------------------- QKV via MFMA (no LDS, no barriers)
// y = x @ W^T per head; W bf16 [e_out=64][d_in=64]. Block: 64 tokens x 1 head, 4 waves.
__global__ __launch_bounds__(256) void qkvm_kernel(const unsigned short* __restrict__ hbf,
    const unsigned short* __restrict__ wqb, const unsigned short* __restrict__ wkb,
    const unsigned short* __restrict__ wvb,
    unsigned short* __restrict__ q, unsigned short* __restrict__ k, unsigned short* __restrict__ v) {
  int tid = threadIdx.x, ln = tid & 63, w = tid >> 6;
  int l15 = ln & 15, lg = ln >> 4;
  int st = blockIdx.x, hh = blockIdx.y;
  int t0 = st * 64 + w * 16;                  // token base (t = b*1024+s flattened)
  const unsigned short* xp = hbf + (size_t)(t0 + l15) * 1024 + hh * 64 + lg * 8;
  bf16x8 xa0 = asbf(*(const u16x8*)xp);
  bf16x8 xa1 = asbf(*(const u16x8*)(xp + 32));
  const unsigned short* wp[3] = {wqb, wkb, wvb};
  unsigned short* outp[3] = {q, k, v};
  f32x4 acc[3][4] = {};
#pragma unroll
  for (int m = 0; m < 3; ++m) {
    __builtin_amdgcn_s_setprio(1);
#pragma unroll
    for (int ni = 0; ni < 4; ++ni) {
      const unsigned short* wb = wp[m] + (size_t)(ni * 16 + l15) * 64 + lg * 8;
      bf16x8 w0 = asbf(*(const u16x8*)wb);
      bf16x8 w1 = asbf(*(const u16x8*)(wb + 32));
      acc[m][ni] = __builtin_amdgcn_mfma_f32_16x16x32_bf16(xa0, w0, acc[m][ni], 0, 0, 0);
      acc[m][ni] = __builtin_amdgcn_mfma_f32_16x16x32_bf16(xa1, w1, acc[m][ni], 0, 0, 0);
    }
    __builtin_amdgcn_s_setprio(0);
  }
#pragma unroll
  for (int m = 0; m < 3; ++m)
#pragma unroll
    for (int ni = 0; ni < 4; ++ni)
#pragma unroll
      for (int r = 0; r < 4; ++r)
        outp[m][(size_t)(t0 + 4 * lg + r) * 1024 + hh * 64 + ni * 16 + l15] = f2bf(acc[m][ni][r]);
}

// ---------------------------------------------------------------- V transpose: [b,s,h,e] -> [b,h,e,s]
__global__ __launch_bounds__(256) void vtrans_kernel(const unsigned short* __restrict__ v,
                                                     unsigned short* __restrict__ vt) {
  __shared__ unsigned short T[64 * 72];
  int tid = threadIdx.x, st = blockIdx.x, bh = blockIdx.y;
  int b = bh >> 4, hh = bh & 15;
  for (int j = 0; j < 2; ++j) {
    int idx = tid + 256 * j; int s = idx >> 3, e0 = (idx & 7) * 8;
    u16x8 r = *(const u16x8*)(v + ((size_t)(b * 1024 + st * 64 + s) * 16 + hh) * 64 + e0);
    for (int i = 0; i < 8; ++i) T[(e0 + i) * 72 + s] = r[i];
  }
  __syncthreads();
  for (int j = 0; j < 2; ++j) {
    int idx = tid + 256 * j; int e = idx >> 3, s0 = (idx & 7) * 8;
    u16x8 r = *(const u16x8*)(&T[e * 72 + s0]);
    *(u16x8*)(vt + ((size_t)(b * 16 + hh) * 64 + e) * 1024 + st * 64 + s0) = r;
  }
}

// ---------------------------------------------------------------- flash attention, KVBLK=128, T14+T5
__global__ __launch_bounds__(256, 2) void attn_kernel(const unsigned short* __restrict__ qb,
    const unsigned short* __restrict__ kb, const unsigned short* __restrict__ vtb,
    unsigned short* __restrict__ ob) {
  constexpr int PK = 72, PV = 136, PP = 136;
  __shared__ unsigned short Ks[128 * PK], Vs[64 * PV], Ps[4][16 * PP];
  int tid = threadIdx.x, lane = tid & 63, w = tid >> 6;
  int l15 = lane & 15, lg = lane >> 4;
  int qt = blockIdx.x, bh = blockIdx.y, b = bh >> 4, hh = bh & 15;
  int q0 = qt * 64 + w * 16;
  const unsigned short* qrow = qb + ((size_t)(b * 1024 + q0 + l15) * 16 + hh) * 64 + lg * 8;
  bf16x8 qa0 = asbf(*(const u16x8*)qrow);
  bf16x8 qa1 = asbf(*(const u16x8*)(qrow + 32));
  float m_[4] = {-1e30f, -1e30f, -1e30f, -1e30f};
  float ls[4] = {0.f, 0.f, 0.f, 0.f};
  f32x4 oacc[4] = {};
  const float inv = 1.f / 32.f;

  u16x8 KR[4], VR[4];                         // T14: reg-staged next tile
  auto loadT = [&](int kt) {
#pragma unroll
    for (int j = 0; j < 4; ++j) {
      int idx = tid + 256 * j;
      int r = idx >> 3, c0 = (idx & 7) * 8;
      KR[j] = *(const u16x8*)(kb + ((size_t)(b * 1024 + kt * 128 + r) * 16 + hh) * 64 + c0);
      int rv = idx >> 4, cv = (idx & 15) * 8;
      VR[j] = *(const u16x8*)(vtb + ((size_t)((b * 16 + hh) * 64) + rv) * 1024 + kt * 128 + cv);
    }
  };
  auto writeT = [&]() {
#pragma unroll
    for (int j = 0; j < 4; ++j) {
      int idx = tid + 256 * j;
      int r = idx >> 3, c0 = (idx & 7) * 8;
      *(u16x8*)(&Ks[r * PK + c0]) = KR[j];
      int rv = idx >> 4, cv = (idx & 15) * 8;
      *(u16x8*)(&Vs[rv * PV + cv]) = VR[j];
    }
  };
  loadT(0); writeT();
  __syncthreads();

  for (int kt = 0; kt < 8; ++kt) {
    f32x4 sf[8] = {};
    __builtin_amdgcn_s_setprio(1);
#pragma unroll
    for (int n = 0; n < 8; ++n) {
      bf16x8 k0 = asbf(*(const u16x8*)(&Ks[(n * 16 + l15) * PK + lg * 8]));
      bf16x8 k1 = asbf(*(const u16x8*)(&Ks[(n * 16 + l15) * PK + 32 + lg * 8]));
      sf[n] = __builtin_amdgcn_mfma_f32_16x16x32_bf16(qa0, k0, sf[n], 0, 0, 0);
      sf[n] = __builtin_amdgcn_mfma_f32_16x16x32_bf16(qa1, k1, sf[n], 0, 0, 0);
    }
    __builtin_amdgcn_s_setprio(0);
    if (kt < 7) loadT(kt + 1);                // issue-early: latency hides under softmax+PV
#pragma unroll
    for (int n = 0; n < 8; ++n) sf[n] *= inv;
    float mx[4], sc[4];
#pragma unroll
    for (int r = 0; r < 4; ++r) {
      float t0 = fmaxf(fmaxf(fmaxf(sf[0][r], sf[1][r]), fmaxf(sf[2][r], sf[3][r])),
                       fmaxf(fmaxf(sf[4][r], sf[5][r]), fmaxf(sf[6][r], sf[7][r])));
      for (int msk = 1; msk < 16; msk <<= 1) t0 = fmaxf(t0, __shfl_xor(t0, msk));
      mx[r] = fmaxf(m_[r], t0);
      sc[r] = __expf(m_[r] - mx[r]);
      m_[r] = mx[r];
    }
    float rsum[4] = {0.f, 0.f, 0.f, 0.f};
    unsigned short pb[8][4];
#pragma unroll
    for (int n = 0; n < 8; ++n)
#pragma unroll
      for (int r = 0; r < 4; ++r) {
        float pv = __expf(sf[n][r] - mx[r]);
        rsum[r] += pv;
        pb[n][r] = f2bf(pv);
      }
#pragma unroll
    for (int r = 0; r < 4; ++r) {
      float t0 = rsum[r];
      for (int msk = 1; msk < 16; msk <<= 1) t0 += __shfl_xor(t0, msk);
      ls[r] = ls[r] * sc[r] + t0;
    }
#pragma unroll
    for (int n = 0; n < 4; ++n)
#pragma unroll
      for (int r = 0; r < 4; ++r) oacc[n][r] *= sc[r];
    unsigned short* pw = Ps[w];                // per-wave region: no block barrier needed
#pragma unroll
    for (int n = 0; n < 8; ++n)
#pragma unroll
      for (int r = 0; r < 4; ++r)
        pw[(4 * lg + r) * PP + n * 16 + l15] = pb[n][r];
    asm volatile("s_waitcnt lgkmcnt(0)" ::: "memory");
    __builtin_amdgcn_sched_barrier(0);
    bf16x8 pa[4];
#pragma unroll
    for (int ks = 0; ks < 4; ++ks)
      pa[ks] = asbf(*(const u16x8*)(&pw[l15 * PP + ks * 32 + lg * 8]));
    __builtin_amdgcn_s_setprio(1);
#pragma unroll
    for (int n = 0; n < 4; ++n) {
#pragma unroll
      for (int ks = 0; ks < 4; ++ks) {
        bf16x8 v0 = asbf(*(const u16x8*)(&Vs[(n * 16 + l15) * PV + ks * 32 + lg * 8]));
        oacc[n] = __builtin_amdgcn_mfma_f32_16x16x32_bf16(pa[ks], v0, oacc[n], 0, 0, 0);
      }
    }
    __builtin_amdgcn_s_setprio(0);
    __syncthreads();                          // all waves done reading tile kt
    if (kt < 7) { writeT(); __syncthreads(); }// write-late: stage visible for next iter
  }
#pragma unroll
  for (int n = 0; n < 4; ++n)
#pragma unroll
    for (int r = 0; r < 4; ++r) {
      float o = oacc[n][r] / ls[r];
      ob[((size_t)(b * 1024 + q0 + 4 * lg + r) * 16 + hh) * 64 + n * 16 + l15] = f2bf(o);
    }
}

// ---------------------------------------------------------------- bf16 GEMM, m97 structure (layer GEMMs)
template <int BM, int KSPLIT, int EPI>
__global__ __launch_bounds__(256) void gemm_kernel(
    const unsigned short* __restrict__ A, int lda,
    const unsigned short* __restrict__ B, int ldb,
    const float* __restrict__ bias,
    float* __restrict__ CfA, float* __restrict__ CfB, unsigned short* __restrict__ Cb,
    int ldc, int Ksub) {
  constexpr int LOGMT = (BM == 128) ? 4 : 5;  // M = 2048 always
  constexpr int MT = 2048 / BM;
  constexpr int MI = BM / 32;                 // A-frags per wave
  __shared__ alignas(16) char smem[33280];    // max(stage 32KB, Cs 64*130*4)
  unsigned short* As = (unsigned short*)smem;           // [2][BM*32]
  unsigned short* Bs = As + 2 * BM * 32;                // [2][128*32]
  float* Cs = (float*)smem;                             // epilogue bounce, stride 130

  int wg = blockIdx.x;
  int mt = wg & (MT - 1);
  int rest = wg >> LOGMT;
  int nt, kh;
  if (KSPLIT == 2) { nt = rest & 7; kh = rest >> 3; }   // NT must be 8 when split
  else { nt = rest; kh = 0; }
  int m0 = mt * BM, n0 = nt * 128;
  const unsigned short* Ae = A + (KSPLIT == 2 ? (size_t)kh * Ksub : 0);
  const unsigned short* Be = B + (KSPLIT == 2 ? (size_t)kh * Ksub : 0);

  int tid = threadIdx.x, ln = tid & 63, wv = tid >> 6;
  int l15 = ln & 15, lg = ln >> 4;
  int wm = (wv >> 1) * (BM / 2), wn = (wv & 1) * 64;

  auto stage = [&](int buf, int k0) {
    for (int j = 0; j < BM / 64; ++j) {
      int row = j * 64 + wv * 16 + (ln >> 2);
      gload16(Ae + (size_t)(m0 + row) * lda + k0 + (ln & 3) * 8,
              &As[buf * (BM * 32) + (j * 64 + wv * 16) * 32]);
    }
    for (int j = 0; j < 2; ++j) {
      int row = j * 64 + wv * 16 + (ln >> 2);
      gload16(Be + (size_t)(n0 + row) * ldb + k0 + (ln & 3) * 8,
              &Bs[buf * 4096 + (j * 64 + wv * 16) * 32]);
    }
  };

  f32x4 acc[MI][4] = {};
  auto compute = [&](int buf) {
    const unsigned short* as = &As[buf * (BM * 32)];
    const unsigned short* bs = &Bs[buf * 4096];
    bf16x8 af[MI], bfn[4];
    for (int mi = 0; mi < MI; ++mi)
      af[mi] = asbf(*(const u16x8*)&as[(wm + mi * 16 + l15) * 32 + lg * 8]);
    for (int ni = 0; ni < 4; ++ni)
      bfn[ni] = asbf(*(const u16x8*)&bs[(wn + ni * 16 + l15) * 32 + lg * 8]);
    for (int mi = 0; mi < MI; ++mi)
      for (int ni = 0; ni < 4; ++ni)
        acc[mi][ni] = __builtin_amdgcn_mfma_f32_16x16x32_bf16(af[mi], bfn[ni], acc[mi][ni], 0, 0, 0);
  };

  stage(0, 0);
  __syncthreads();
  int ntk = Ksub >> 5, cur = 0;
  for (int t = 0; t < ntk - 1; ++t) {
    stage(cur ^ 1, (t + 1) << 5);
    compute(cur);
    __syncthreads();
    cur ^= 1;
  }
  compute(cur);

  float* Cf = (kh == 0) ? CfA : CfB;
  const bool addb = (kh == 0);
  for (int p = 0; p < BM / 64; ++p) {
    __syncthreads();
    if ((wm >> 6) == p) {
      int rb = wm & 63;
      for (int mi = 0; mi < MI; ++mi)
        for (int ni = 0; ni < 4; ++ni) {
          int cn = wn + ni * 16 + l15;
          float bv = addb ? bias[n0 + cn] : 0.f;
          for (int r = 0; r < 4; ++r) {
            float vv = acc[mi][ni][r] + bv;
            if (EPI == 1) vv = 0.5f * vv * (1.f + erff(vv * 0.70710678118f));
            Cs[(rb + mi * 16 + 4 * lg + r) * 130 + cn] = vv;
          }
        }
    }
    __syncthreads();
    int row = tid >> 3;
    for (int ri = 0; ri < 2; ++ri) {
      int lr = ri * 32 + row;
      size_t gbase = (size_t)(m0 + p * 64 + lr) * ldc + n0;
      if (EPI == 0) {
        int c4 = (tid & 7) * 4;
        for (int j = 0; j < 4; ++j)
          *(f32x4*)(Cf + gbase + c4 + j * 32) = *(const f32x4*)&Cs[lr * 130 + c4 + j * 32];
      } else {
        for (int j = 0; j < 2; ++j) {
          int cc = (tid & 7) * 8 + j * 64;
          f32x4 v0 = *(const f32x4*)&Cs[lr * 130 + cc];
          f32x4 v1 = *(const f32x4*)&Cs[lr * 130 + cc + 4];
          u16x8 o;
          for (int i = 0; i < 4; ++i) { o[i] = f2bf(v0[i]); o[i + 4] = f2bf(v1[i]); }
          *(u16x8*)(Cb + gbase + cc) = o;
        }
      }
    }
  }
}

// ---------------------------------------------------------------- 256x256 BK=64 4-phase GEMM (logits)
// Counted-vmcnt schedule (T4): deadline-ordered half-tile staging, waits 6/6/-/4, never 0 mid-loop.
__global__ __launch_bounds__(512, 1) void gemm256_kernel(
    const unsigned short* __restrict__ A, int lda,
    const unsigned short* __restrict__ B, int ldb,
    const float* __restrict__ bias, float* __restrict__ C, int ldc, int K) {
  extern __shared__ unsigned short sm[];      // 65536 elems = 128 KiB
  int b = blockIdx.x;
  int c = (int)gridDim.x >> 3;
  int wg = (b & 7) * c + (b >> 3);            // XCD-contiguous (grid % 8 == 0)
  int mt = wg & 7, nt = wg >> 3;
  int m0 = mt * 256, n0 = nt * 256;

  int tid = threadIdx.x, ln = tid & 63, wv = tid >> 6;
  int l15 = ln & 15, lg = ln >> 4;
  int wm = wv >> 2, wn = wv & 3;              // 2M x 4N waves; wave tile 128x64
  int l7 = l15 & 7;

  int srow = tid >> 3, sblk = (tid & 7) ^ (srow & 7);
  const unsigned short* Ab = A + (size_t)(m0 + srow) * lda + sblk * 8;
  const unsigned short* BbG[4];
#pragma unroll
  for (int g = 0; g < 4; ++g) {
    int p = g * 64 + srow;
    int j = p & 127;
    int r = ((j >> 5) << 6) + ((p >> 7) << 5) + (j & 31);
    BbG[g] = B + (size_t)(n0 + r) * ldb + sblk * 8;
  }
  auto stA = [&](int e, int g, int k0) {
    gload16(Ab + ((size_t)g * 64) * lda + k0, &sm[e * 16384 + g * 4096 + wv * 512]);
  };
  auto stB = [&](int e, int g, int k0) {
    gload16(BbG[g] + k0, &sm[32768 + e * 16384 + g * 4096 + wv * 512]);
  };

  auto ldsA = [&](int d, int mi, int ks) -> bf16x8 {
    int row = wm * 128 + mi * 16 + l15;
    return asbf(*(const u16x8*)&sm[d * 16384 + row * 64 + (((ks << 2) | lg) ^ l7) * 8]);
  };
  auto ldsB = [&](int d, int ni, int ks) -> bf16x8 {
    int p = ((ni >> 1) << 7) + wn * 32 + ((ni & 1) << 4) + l15;   // permuted row
    return asbf(*(const u16x8*)&sm[32768 + d * 16384 + p * 64 + (((ks << 2) | lg) ^ l7) * 8]);
  };

  f32x4 acc[8][4] = {};
  bf16x8 Af[4][2], Bf01[2][2], Bf23[2][2];

#define PH_OPEN() __builtin_amdgcn_s_barrier(); \
  asm volatile("s_waitcnt lgkmcnt(0)" ::: "memory"); \
  __builtin_amdgcn_sched_barrier(0); __builtin_amdgcn_s_setprio(1)

  stA(0, 0, 0); stA(0, 2, 0); stB(0, 0, 0); stB(0, 1, 0);
  stB(0, 2, 0); stB(0, 3, 0); stA(0, 1, 0); stA(0, 3, 0);
  asm volatile("s_waitcnt vmcnt(0)" ::: "memory");
  __builtin_amdgcn_s_barrier();

  int ntk = K >> 6;
  for (int kk = 0; kk < ntk; ++kk) {
    int d = kk & 1, e = d ^ 1, k1 = (kk + 1) << 6;
    bool pf = (kk + 1 < ntk);
    { // P1
#pragma unroll
      for (int ni = 0; ni < 2; ++ni) { Bf01[ni][0] = ldsB(d, ni, 0); Bf01[ni][1] = ldsB(d, ni, 1); }
#pragma unroll
      for (int mi = 0; mi < 4; ++mi) { Af[mi][0] = ldsA(d, mi, 0); Af[mi][1] = ldsA(d, mi, 1); }
      if (pf) { stA(e, 0, k1); stA(e, 2, k1); stB(e, 0, k1); stB(e, 1, k1); }
      PH_OPEN();
#pragma unroll
      for (int mi = 0; mi < 4; ++mi)
#pragma unroll
        for (int ni = 0; ni < 2; ++ni) {
          acc[mi][ni] = __builtin_amdgcn_mfma_f32_16x16x32_bf16(Af[mi][0], Bf01[ni][0], acc[mi][ni], 0, 0, 0);
          acc[mi][ni] = __builtin_amdgcn_mfma_f32_16x16x32_bf16(Af[mi][1], Bf01[ni][1], acc[mi][ni], 0, 0, 0);
        }
      __builtin_amdgcn_s_setprio(0);
      if (pf) { asm volatile("s_waitcnt vmcnt(6)" ::: "memory"); }
      else    { asm volatile("s_waitcnt vmcnt(2)" ::: "memory"); }
      __builtin_amdgcn_s_barrier();
    }
    { // P2
#pragma unroll
      for (int ni = 0; ni < 2; ++ni) { Bf23[ni][0] = ldsB(d, 2 + ni, 0); Bf23[ni][1] = ldsB(d, 2 + ni, 1); }
      if (pf) { stB(e, 2, k1); stB(e, 3, k1); }
      PH_OPEN();
#pragma unroll
      for (int mi = 0; mi < 4; ++mi)
#pragma unroll
        for (int ni = 0; ni < 2; ++ni) {
          acc[mi][2 + ni] = __builtin_amdgcn_mfma_f32_16x16x32_bf16(Af[mi][0], Bf23[ni][0], acc[mi][2 + ni], 0, 0, 0);
          acc[mi][2 + ni] = __builtin_amdgcn_mfma_f32_16x16x32_bf16(Af[mi][1], Bf23[ni][1], acc[mi][2 + ni], 0, 0, 0);
        }
      __builtin_amdgcn_s_setprio(0);
      if (pf) { asm volatile("s_waitcnt vmcnt(6)" ::: "memory"); }
      else    { asm volatile("s_waitcnt vmcnt(0)" ::: "memory"); }
      __builtin_amdgcn_s_barrier();
    }
    { // P3
#pragma unroll
      for (int mi = 0; mi < 4; ++mi) { Af[mi][0] = ldsA(d, 4 + mi, 0); Af[mi][1] = ldsA(d, 4 + mi, 1); }
      if (pf) { stA(e, 1, k1); stA(e, 3, k1); }
      PH_OPEN();
#pragma unroll
      for (int mi = 0; mi < 4; ++mi)
#pragma unroll
        for (int ni = 0; ni < 2; ++ni) {
          acc[4 + mi][2 + ni] = __builtin_amdgcn_mfma_f32_16x16x32_bf16(Af[mi][0], Bf23[ni][0], acc[4 + mi][2 + ni], 0, 0, 0);
          acc[4 + mi][2 + ni] = __builtin_amdgcn_mfma_f32_16x16x32_bf16(Af[mi][1], Bf23[ni][1], acc[4 + mi][2 + ni], 0, 0, 0);
        }
      __builtin_amdgcn_s_setprio(0);
      __builtin_amdgcn_s_barrier();
    }
    { // P4
      PH_OPEN();
#pragma unroll
      for (int mi = 0; mi < 4; ++mi)
#pragma unroll
        for (int ni = 0; ni < 2; ++ni) {
          acc[4 + mi][ni] = __builtin_amdgcn_mfma_f32_16x16x32_bf16(Af[mi][0], Bf01[ni][0], acc[4 + mi][ni], 0, 0, 0);
          acc[4 + mi][ni] = __builtin_amdgcn_mfma_f32_16x16x32_bf16(Af[mi][1], Bf01[ni][1], acc[4 + mi][ni], 0, 0, 0);
        }
      __builtin_amdgcn_s_setprio(0);
      if (pf) { asm volatile("s_waitcnt vmcnt(4)" ::: "memory"); }
      __builtin_amdgcn_s_barrier();
    }
  }
#undef PH_OPEN

  float* fb = (float*)sm;
  int fbase = wv * 4096;
  float bv[4];
#pragma unroll
  for (int ni = 0; ni < 4; ++ni) bv[ni] = bias[n0 + wn * 64 + ni * 16 + l15];
#pragma unroll
  for (int p = 0; p < 2; ++p) {
    if (p) { asm volatile("s_waitcnt lgkmcnt(0)" ::: "memory"); __builtin_amdgcn_sched_barrier(0); }
#pragma unroll
    for (int mi = 0; mi < 4; ++mi)
#pragma unroll
      for (int ni = 0; ni < 4; ++ni)
#pragma unroll
        for (int r = 0; r < 4; ++r)
          fb[fbase + (mi * 16 + lg * 4 + r) * 64 + ni * 16 + l15] = acc[4 * p + mi][ni][r] + bv[ni];
    asm volatile("s_waitcnt lgkmcnt(0)" ::: "memory");
    __builtin_amdgcn_sched_barrier(0);
#pragma unroll
    for (int i = 0; i < 16; ++i) {
      int row = i * 4 + lg;
      f32x4 v = *(const f32x4*)&fb[fbase + row * 64 + l15 * 4];
      int grow = m0 + wm * 128 + p * 64 + row;
      *(f32x4*)(&C[(size_t)grow * ldc + n0 + wn * 64 + l15 * 4]) = v;
    }
  }
}

// ----------------------------------------------------------------
extern "C" void kernel_launch(void* const* d_in, const int* in_sizes, int n_in,
                              void* d_out, int out_size, void* d_ws, size_t ws_size,
                              hipStream_t stream) {
  const int* x = (const int*)d_in[0];
  const float* tok = (const float*)d_in[1];
  const float* pos = (const float*)d_in[2];
  const float* wq = (const float*)d_in[3];
  const float* wk = (const float*)d_in[4];
  const float* wv = (const float*)d_in[5];
  const float* wo = (const float*)d_in[6];
  const float* bo = (const float*)d_in[7];
  const float* ln1g = (const float*)d_in[8];
  const float* ln1b = (const float*)d_in[9];
  const float* ln2g = (const float*)d_in[10];
  const float* ln2b = (const float*)d_in[11];
  const float* w1 = (const float*)d_in[12];
  const float* b1 = (const float*)d_in[13];
  const float* w2 = (const float*)d_in[14];
  const float* b2 = (const float*)d_in[15];
  const float* outw = (const float*)d_in[16];
  const float* outb = (const float*)d_in[17];
  float* out = (float*)d_out;

  const size_t MiB = 1 << 20;
  const size_t need = 4 * MiB + 65536000;
  if (ws_size < need) return;
  char* base = (char*)d_ws;
  unsigned short* hbf = (unsigned short*)base;            // 4 MiB, persistent
  char* R = base + 4 * MiB;
  float* hf  = (float*)(R);                               // 8 MiB
  float* x1f = (float*)(R + 8 * MiB);                     // 8 MiB
  unsigned short* x1bf = (unsigned short*)(R + 16 * MiB); // 4 MiB
  float* cfA = (float*)(R + 20 * MiB);                    // 8 MiB
  float* cfB = (float*)(R + 28 * MiB);                    // 8 MiB
  unsigned short* qs = (unsigned short*)(R + 36 * MiB);   // 6 slots x 4 MiB
  const size_t SL = 2048ull * 1024;
  unsigned short* qbf = qs;
  unsigned short* kbf = qs + SL;
  unsigned short* vbf = qs + 2 * SL;                      // also attn-out
  unsigned short* vtbf = qs + 3 * SL;                     // also wobf
  unsigned short* wobf = vtbf;
  unsigned short* w1bf = qbf;
  unsigned short* w2bf = qbf;
  unsigned short* ffbf = vbf;
  unsigned short* wqbf = (unsigned short*)(R + 60 * MiB); // 3 x 16384 u16 (96 KB, layers only)
  unsigned short* wkbf = wqbf + 16384;
  unsigned short* wvbf = wkbf + 16384;
  unsigned short* outwbf = (unsigned short*)R;            // 62.5 MiB, after layers

  embed_kernel<<<2048, 256, 0, stream>>>(x, tok, pos, hf, hbf);
  cvt_kernel<<<8, 256, 0, stream>>>(wq, wqbf, 2048);      // all 4 layers' qkv weights -> bf16
  cvt_kernel<<<8, 256, 0, stream>>>(wk, wkbf, 2048);
  cvt_kernel<<<8, 256, 0, stream>>>(wv, wvbf, 2048);
  for (int l = 0; l < 4; ++l) {
    qkvm_kernel<<<dim3(32, 16), 256, 0, stream>>>(hbf, wqbf + l * 4096, wkbf + l * 4096,
                                                  wvbf + l * 4096, qbf, kbf, vbf);
    vtrans_kernel<<<dim3(16, 32), 256, 0, stream>>>(vbf, vtbf);
    attn_kernel<<<dim3(16, 32), 256, 0, stream>>>(qbf, kbf, vtbf, vbf);
    cvt_kernel<<<512, 256, 0, stream>>>(wo + (size_t)l * 1048576, wobf, 131072);
    cvt_kernel<<<2048, 256, 0, stream>>>(w1 + (size_t)l * 4194304, w1bf, 524288);
    gemm_kernel<64, 2, 0><<<512, 256, 0, stream>>>(
        vbf, 1024, wobf, 1024, bo + l * 1024, cfA, cfB, nullptr, 1024, 512);
    ln_kernel<<<2048, 256, 0, stream>>>(cfA, cfB, hf, ln1g + l * 1024, ln1b + l * 1024,
                                        x1f, x1bf);
    gemm_kernel<128, 1, 1><<<512, 256, 0, stream>>>(
        x1bf, 1024, w1bf, 1024, b1 + l * 4096, nullptr, nullptr, ffbf, 4096, 1024);
    cvt_kernel<<<2048, 256, 0, stream>>>(w2 + (size_t)l * 4194304, w2bf, 524288);
    gemm_kernel<64, 2, 0><<<512, 256, 0, stream>>>(
        ffbf, 4096, w2bf, 4096, b2 + l * 1024, cfA, cfB, nullptr, 1024, 2048);
    ln_kernel<<<2048, 256, 0, stream>>>(cfA, cfB, x1f, ln2g + l * 1024, ln2b + l * 1024,
                                        hf, hbf);
  }
  cvt_kernel<<<2048, 256, 0, stream>>>(outw, outwbf, 4096000);
  gemm256_kernel<<<1000, 512, 131072, stream>>>(hbf, 1024, outwbf, 1024, outb, out, 32000, 1024);
}